// Round 3
// baseline (15260.484 us; speedup 1.0000x reference)
//
#include <hip/hip_runtime.h>
#include <math.h>

#define NLAY 2
#define BB 16
#define LL 8192
#define HH 128
#define PP 64
#define CIN 64
#define CHS 128           // scan chunk size
#define NCH 64            // LL/CHS
#define ROWS (BB*LL)      // 131072

// ---- workspace layout (float offsets) ---- total ~194.4 MiB
#define OFF_H   0ul
#define OFF_A   16777216ul
#define OFF_B   33554432ul
#define OFF_EF  50331648ul            // 8 arrays x 65536 floats (2 MiB); reused for pool partials at end
#define OFF_PC  (OFF_EF + 524288ul)
#define PCS     49408ul               // per-layer: W_bu[16384] W_y[32768] lbar/lch consts

__device__ __forceinline__ float gelu_(float x){
  return 0.5f*x*(1.0f + erff(x*0.70710678118654752440f));
}

// ---------------- precompute: discretization + packed weight matrices ----------------
__global__ void k_pre(const float* __restrict__ Lam_re, const float* __restrict__ Lam_im,
                      const float* __restrict__ B_re, const float* __restrict__ B_im,
                      const float* __restrict__ C_re, const float* __restrict__ C_im,
                      const float* __restrict__ log_step, float* __restrict__ ws)
{
  int i = blockIdx.x, tid = threadIdx.x;
  float* pc = ws + OFF_PC + (unsigned long)i*PCS;
  __shared__ float qre[PP], qim[PP];
  if (tid < PP){
    int p = tid;
    float lre = Lam_re[i*PP+p], lim = Lam_im[i*PP+p];
    float st = expf(log_step[i*PP+p]);
    float er = expf(lre*st), ang = lim*st;
    float Lr = er*cosf(ang);
    float Li = er*sinf(ang);
    float wr = Lr - 1.0f, wi = Li;
    float den = lre*lre + lim*lim;
    qre[p] = (wr*lre + wi*lim)/den;
    qim[p] = (wi*lre - wr*lim)/den;
    pc[49152+p] = Lr; pc[49216+p] = Li;
    float ec = expf(lre*st*(float)CHS), ac = lim*st*(float)CHS;
    pc[49280+p] = ec*cosf(ac); pc[49344+p] = ec*sinf(ac);
  }
  __syncthreads();
  // W_bu[h][c*64+p] = (c? Bbar_im : Bbar_re)[p][h],  Bbar = q * (B_re + i B_im)
  for (int k = 0; k < 64; k++){
    int e = tid + k*256;
    int h = e>>7, j = e&127, c = j>>6, p = j&63;
    float br = B_re[(i*PP+p)*HH + h], bi = B_im[(i*PP+p)*HH + h];
    pc[e] = c ? (qre[p]*bi + qim[p]*br) : (qre[p]*br - qim[p]*bi);
  }
  // W_y[k][h], k = c*64+p : +Cre[h][p], -Cim[h][p], +Cre[h][64+p], -Cim[h][64+p]
  for (int k = 0; k < 128; k++){
    int e = tid + k*256;
    int kk = e>>7, h = e&127, c = kk>>6, p = kk&63;
    float v;
    int base = (i*HH + h)*(2*PP);
    if      (c==0) v =  C_re[base + p];
    else if (c==1) v = -C_im[base + p];
    else if (c==2) v =  C_re[base + PP + p];
    else           v = -C_im[base + PP + p];
    pc[16384 + e] = v;
  }
}

// ---------------- input projection: h[b,l,:] = x[b,:,l]^T @ W_in + b_in ----------------
__global__ void k_inproj(const float* __restrict__ x, const float* __restrict__ W_in,
                         const float* __restrict__ b_in, float* __restrict__ hout)
{
  __shared__ float s[256*33];
  int tid = threadIdx.x;
  int b = blockIdx.y;
  int l0 = blockIdx.x*256;
  float acc[128];
  #pragma unroll
  for (int j=0;j<128;j++) acc[j] = b_in[j];
  for (int kc=0; kc<2; kc++){
    __syncthreads();
    #pragma unroll
    for (int k2=0;k2<32;k2++){
      int e = tid + k2*256; int ll = e&255, cc = e>>8;
      s[ll*33+cc] = x[((long)b*CIN + kc*32+cc)*LL + l0 + ll];
    }
    __syncthreads();
    #pragma unroll 2
    for (int kk=0;kk<32;kk++){
      float a = s[tid*33+kk];
      const float* wr = W_in + (kc*32+kk)*HH;
      #pragma unroll
      for (int j=0;j<128;j++) acc[j] += a*wr[j];
    }
  }
  long g0 = (long)b*LL + l0;
  for (int jc=0;jc<4;jc++){
    __syncthreads();
    #pragma unroll
    for (int jj=0;jj<32;jj++) s[tid*33+jj] = acc[jc*32+jj];
    __syncthreads();
    #pragma unroll
    for (int k2=0;k2<32;k2++){
      int e = tid + k2*256; int r = e>>5, jj = e&31;
      hout[(g0+r)*HH + jc*32 + jj] = s[r*33+jj];
    }
  }
}

// ---------------- fused LN1 + Bu matmul: bu[row][re(64)|im(64)] = LN(h) @ W_bu ----------------
__global__ void k_bu2(const float* __restrict__ h, const float* __restrict__ W,
                      const float* __restrict__ g, const float* __restrict__ bta,
                      float* __restrict__ bu)
{
  __shared__ float s[256*33];
  int tid = threadIdx.x; long g0 = (long)blockIdx.x*256;
  // pass 1: LN stats for own row
  float sum=0.f, sq=0.f;
  for (int kc=0;kc<4;kc++){
    __syncthreads();
    #pragma unroll
    for (int k2=0;k2<32;k2++){ int e=tid+k2*256; int r=e>>5, kk=e&31;
      s[r*33+kk] = h[(g0+r)*HH + kc*32 + kk]; }
    __syncthreads();
    #pragma unroll
    for (int kk=0;kk<32;kk++){ float v = s[tid*33+kk]; sum += v; sq += v*v; }
  }
  float m = sum*(1.0f/HH);
  float inv = 1.0f/sqrtf(sq*(1.0f/HH) - m*m + 1e-5f);
  // pass 2: matmul with on-the-fly LN
  float acc[128];
  #pragma unroll
  for (int j=0;j<128;j++) acc[j]=0.f;
  for (int kc=0;kc<4;kc++){
    __syncthreads();
    #pragma unroll
    for (int k2=0;k2<32;k2++){ int e=tid+k2*256; int r=e>>5, kk=e&31;
      s[r*33+kk] = h[(g0+r)*HH + kc*32 + kk]; }
    __syncthreads();
    #pragma unroll 2
    for (int kk=0;kk<32;kk++){
      float fx = (s[tid*33+kk]-m)*inv*g[kc*32+kk] + bta[kc*32+kk];
      const float* wr = W + (kc*32+kk)*128;
      #pragma unroll
      for (int j=0;j<128;j++) acc[j] += fx*wr[j];
    }
  }
  for (int jc=0;jc<4;jc++){
    __syncthreads();
    #pragma unroll
    for (int jj=0;jj<32;jj++) s[tid*33+jj] = acc[jc*32+jj];
    __syncthreads();
    #pragma unroll
    for (int k2=0;k2<32;k2++){
      int e = tid + k2*256; int r = e>>5, jj = e&31;
      bu[(g0+r)*HH + jc*32 + jj] = s[r*33+jj];
    }
  }
}

// ---------------- scan phase A: per-chunk fwd/bwd reductions ----------------
__global__ void k_scanA(const float* __restrict__ bu, const float* __restrict__ pc,
                        float* __restrict__ ws)
{
  int p = threadIdx.x; int c = blockIdx.x, b = blockIdx.y;
  float Lr = pc[49152+p], Li = pc[49216+p];
  float efr=0.f, efi=0.f, ebr=0.f, ebi=0.f, pwr=1.f, pwi=0.f;
  long base = ((long)b*LL + (long)c*CHS)*HH;
  for (int i=0;i<CHS;i++){
    float br = bu[base + (long)i*HH + p], bi = bu[base + (long)i*HH + 64 + p];
    float nr = Lr*efr - Li*efi + br;
    efi = Lr*efi + Li*efr + bi; efr = nr;
    ebr += pwr*br - pwi*bi;
    ebi += pwr*bi + pwi*br;
    float tr = pwr*Lr - pwi*Li;
    pwi = pwr*Li + pwi*Lr; pwr = tr;
  }
  long o = ((long)b*NCH + c)*PP + p;
  ws[OFF_EF + o] = efr;            ws[OFF_EF+65536 + o] = efi;
  ws[OFF_EF+131072 + o] = ebr;     ws[OFF_EF+196608 + o] = ebi;
}

// ---------------- scan phase B: carry scan over chunks ----------------
__global__ void k_scanB(const float* __restrict__ pc, float* __restrict__ ws)
{
  int p = threadIdx.x; int b = blockIdx.x;
  float Cr = pc[49280+p], Ci = pc[49344+p];
  float Fr=0.f, Fi=0.f;
  for (int c=0;c<NCH;c++){
    long o = ((long)b*NCH + c)*PP + p;
    ws[OFF_EF+262144 + o] = Fr;
    ws[OFF_EF+327680 + o] = Fi;
    float er = ws[OFF_EF + o], ei = ws[OFF_EF+65536 + o];
    float nr = Cr*Fr - Ci*Fi + er;
    Fi = Cr*Fi + Ci*Fr + ei; Fr = nr;
  }
  float Xr=0.f, Xi=0.f;
  for (int c=NCH-1;c>=0;c--){
    long o = ((long)b*NCH + c)*PP + p;
    ws[OFF_EF+393216 + o] = Xr;
    ws[OFF_EF+458752 + o] = Xi;
    float er = ws[OFF_EF+131072 + o], ei = ws[OFF_EF+196608 + o];
    float nr = er + Cr*Xr - Ci*Xi;
    Xi = ei + Cr*Xi + Ci*Xr; Xr = nr;
  }
}

// ---------------- scan phase C: xf in-place over bu; xb -> A ----------------
// lane p only touches offsets p and 64+p of each row: race-free in-place.
__global__ void k_scanC(float* __restrict__ bu, float* __restrict__ xb,
                        const float* __restrict__ pc, const float* __restrict__ wsc)
{
  __shared__ float sbr[CHS*PP], sbi[CHS*PP];
  int p = threadIdx.x; int c = blockIdx.x, b = blockIdx.y;
  float Lr = pc[49152+p], Li = pc[49216+p];
  long o = ((long)b*NCH + c)*PP + p;
  float xr = wsc[OFF_EF+262144 + o], xi = wsc[OFF_EF+327680 + o];
  long base = ((long)b*LL + (long)c*CHS)*HH;
  for (int i=0;i<CHS;i++){
    long a0 = base + (long)i*HH;
    float br = bu[a0+p], bi = bu[a0+64+p];
    sbr[i*PP+p] = br; sbi[i*PP+p] = bi;
    float nr = Lr*xr - Li*xi + br;
    xi = Lr*xi + Li*xr + bi; xr = nr;
    bu[a0+p] = xr; bu[a0+64+p] = xi;
  }
  float yr = wsc[OFF_EF+393216 + o], yi = wsc[OFF_EF+458752 + o];
  for (int i=CHS-1;i>=0;i--){
    long a0 = base + (long)i*HH;
    float br = sbr[i*PP+p], bi = sbi[i*PP+p];
    float nr = Lr*yr - Li*yi + br;
    yi = Lr*yi + Li*yr + bi; yr = nr;
    xb[a0+p] = yr; xb[a0+64+p] = yi;
  }
}

// ---------------- fused y-matmul + D*fx + gelu + residual + LN2 -> fy (in-place over xf) ----------------
__global__ void k_ymmgly(float* __restrict__ xf, const float* __restrict__ xb,
                         const float* __restrict__ h, const float* __restrict__ Wy,
                         const float* __restrict__ Dv,
                         const float* __restrict__ ag, const float* __restrict__ ab,
                         const float* __restrict__ fg, const float* __restrict__ fb)
{
  __shared__ float s[256*33];
  int tid = threadIdx.x; long g0 = (long)blockIdx.x*256;
  // LN1 stats from h
  float sum=0.f, sq=0.f;
  for (int kc=0;kc<4;kc++){
    __syncthreads();
    #pragma unroll
    for (int k2=0;k2<32;k2++){ int e=tid+k2*256; int r=e>>5, kk=e&31;
      s[r*33+kk] = h[(g0+r)*HH + kc*32 + kk]; }
    __syncthreads();
    #pragma unroll
    for (int kk=0;kk<32;kk++){ float v = s[tid*33+kk]; sum += v; sq += v*v; }
  }
  float m1 = sum*(1.0f/HH);
  float inv1 = 1.0f/sqrtf(sq*(1.0f/HH) - m1*m1 + 1e-5f);
  // y = xs @ W_y  (K=256)
  float acc[128];
  #pragma unroll
  for (int j=0;j<128;j++) acc[j]=0.f;
  for (int kc=0;kc<8;kc++){
    const float* src = (kc<4)? xf : xb;
    int col0 = (kc&3)*32;
    __syncthreads();
    #pragma unroll
    for (int k2=0;k2<32;k2++){ int e=tid+k2*256; int r=e>>5, kk=e&31;
      s[r*33+kk] = src[(g0+r)*HH + col0 + kk]; }
    __syncthreads();
    #pragma unroll 2
    for (int kk=0;kk<32;kk++){
      float a = s[tid*33+kk];
      const float* wr = Wy + (kc*32+kk)*128;
      #pragma unroll
      for (int j=0;j<128;j++) acc[j] += a*wr[j];
    }
  }
  // a = gelu(y + D*fx) + fx ; then LN2 -> fy
  float sum2=0.f, sq2=0.f;
  for (int kc=0;kc<4;kc++){
    __syncthreads();
    #pragma unroll
    for (int k2=0;k2<32;k2++){ int e=tid+k2*256; int r=e>>5, kk=e&31;
      s[r*33+kk] = h[(g0+r)*HH + kc*32 + kk]; }
    __syncthreads();
    #pragma unroll
    for (int kk=0;kk<32;kk++){
      int j = kc*32+kk;
      float fxv = (s[tid*33+kk]-m1)*inv1*ag[j] + ab[j];
      float av = gelu_(acc[j] + Dv[j]*fxv) + fxv;
      acc[j] = av; sum2 += av; sq2 += av*av;
    }
  }
  float m2 = sum2*(1.0f/HH);
  float inv2 = 1.0f/sqrtf(sq2*(1.0f/HH) - m2*m2 + 1e-5f);
  #pragma unroll
  for (int j=0;j<128;j++) acc[j] = (acc[j]-m2)*inv2*fg[j] + fb[j];
  // write fy in-place over xf (own-block rows only; all reads done, barriers since)
  for (int jc=0;jc<4;jc++){
    __syncthreads();
    #pragma unroll
    for (int jj=0;jj<32;jj++) s[tid*33+jj] = acc[jc*32+jj];
    __syncthreads();
    #pragma unroll
    for (int k2=0;k2<32;k2++){
      int e = tid + k2*256; int r = e>>5, jj = e&31;
      xf[(g0+r)*HH + jc*32 + jj] = s[r*33+jj];
    }
  }
}

// ---------------- GEGLU encode: t = v * gelu(g),  e = fy @ W_enc ----------------
__global__ void k_enc(const float* __restrict__ act, const float* __restrict__ Wenc,
                      float* __restrict__ tout)
{
  __shared__ float s[256*33];
  int tid = threadIdx.x; long g0 = (long)blockIdx.x*256;
  for (int half=0; half<2; half++){
    float av[64], agl[64];
    #pragma unroll
    for (int j=0;j<64;j++){ av[j]=0.f; agl[j]=0.f; }
    for (int kc=0;kc<4;kc++){
      __syncthreads();
      #pragma unroll
      for (int k2=0;k2<32;k2++){ int e=tid+k2*256; int r=e>>5, kk=e&31;
        s[r*33+kk] = act[(g0+r)*HH + kc*32 + kk]; }
      __syncthreads();
      #pragma unroll 2
      for (int kk=0;kk<32;kk++){
        float a = s[tid*33+kk];
        const float* wv = Wenc + (kc*32+kk)*256 + half*64;
        const float* wg = wv + 128;
        #pragma unroll
        for (int j=0;j<64;j++){ av[j] += a*wv[j]; agl[j] += a*wg[j]; }
      }
    }
    #pragma unroll
    for (int j=0;j<64;j++) av[j] = av[j]*gelu_(agl[j]);
    for (int jc=0;jc<2;jc++){
      __syncthreads();
      #pragma unroll
      for (int jj=0;jj<32;jj++) s[tid*33+jj] = av[jc*32+jj];
      __syncthreads();
      #pragma unroll
      for (int k2=0;k2<32;k2++){
        int e = tid + k2*256; int r = e>>5, jj = e&31;
        tout[(g0+r)*HH + half*64 + jc*32 + jj] = s[r*33+jj];
      }
    }
  }
}

// ---------------- decode in-place: blk = t @ W_dec over the t buffer ----------------
__global__ void k_dec(float* __restrict__ tb, const float* __restrict__ W)
{
  __shared__ float s[128*128];
  int tid = threadIdx.x; long g0 = (long)blockIdx.x*128;
  for (int it=0; it<128; it++)
    s[it*128 + (tid ^ (it&31))] = tb[(g0+it)*HH + tid];
  __syncthreads();
  float acc[128];
  #pragma unroll
  for (int j=0;j<128;j++) acc[j]=0.f;
  #pragma unroll 2
  for (int k=0;k<128;k++){
    float a = s[tid*128 + (k ^ (tid&31))];
    const float* wr = W + k*128;
    #pragma unroll
    for (int j=0;j<128;j++) acc[j] += a*wr[j];
  }
  __syncthreads();
  #pragma unroll
  for (int j=0;j<128;j++) s[tid*128 + (j ^ (tid&31))] = acc[j];
  __syncthreads();
  for (int it=0; it<128; it++)
    tb[(g0+it)*HH + tid] = s[it*128 + (tid ^ (it&31))];
}

// ---------------- blk + fy + res -> LN -> dst ----------------
__global__ void k_ln3(const float* __restrict__ blk, const float* __restrict__ fy,
                      const float* __restrict__ res, float* __restrict__ dst,
                      const float* __restrict__ g, const float* __restrict__ bta)
{
  int wv = threadIdx.x>>6, lane = threadIdx.x&63;
  long row = (long)blockIdx.x*4 + wv;
  long o = row*HH;
  float a0 = blk[o+lane]    + fy[o+lane]    + res[o+lane];
  float a1 = blk[o+lane+64] + fy[o+lane+64] + res[o+lane+64];
  float sum = a0+a1, sq = a0*a0+a1*a1;
  #pragma unroll
  for (int oo=1;oo<64;oo<<=1){ sum += __shfl_xor(sum,oo); sq += __shfl_xor(sq,oo); }
  float m = sum*(1.0f/HH);
  float var = sq*(1.0f/HH) - m*m;
  float inv = 1.0f/sqrtf(var + 1e-5f);
  dst[o+lane]    = (a0-m)*inv*g[lane]    + bta[lane];
  dst[o+lane+64] = (a1-m)*inv*g[lane+64] + bta[lane+64];
}

// ---------------- mean pool partials ----------------
__global__ void k_pool(const float* __restrict__ hbuf, float* __restrict__ part)
{
  int h = threadIdx.x; int seg = blockIdx.x, b = blockIdx.y;
  float sum=0.f;
  long base = ((long)b*LL + (long)seg*128)*HH + h;
  for (int i=0;i<128;i++) sum += hbuf[base + (long)i*HH];
  part[((long)seg*BB + b)*HH + h] = sum;
}

// ---------------- classifier head (fp32 output) ----------------
__global__ void k_cls(const float* __restrict__ part, const float* __restrict__ Wc1,
                      const float* __restrict__ bc1, const float* __restrict__ Wc2,
                      const float* __restrict__ bc2, float* __restrict__ out)
{
  __shared__ float pooled[BB*HH];
  __shared__ float zs[BB*64];
  int tid = threadIdx.x;
  for (int k=0;k<8;k++){
    int e = tid + k*256; int b = e>>7, hh = e&127;
    float s = 0.f;
    for (int seg=0; seg<64; seg++) s += part[((long)seg*BB + b)*HH + hh];
    pooled[e] = s * (1.0f/(float)LL);
  }
  __syncthreads();
  for (int k=0;k<4;k++){
    int e = tid + k*256; int b = e>>6, j = e&63;
    float s = bc1[j];
    for (int hh=0; hh<HH; hh++) s += pooled[b*HH+hh]*Wc1[hh*64+j];
    zs[e] = fmaxf(s, 0.0f);
  }
  __syncthreads();
  if (tid < BB*3){
    int b = tid/3, cc = tid%3;
    float s = bc2[cc];
    for (int j=0;j<64;j++) s += zs[b*64+j]*Wc2[j*3+cc];
    out[tid] = s;
  }
}

extern "C" void kernel_launch(void* const* d_in, const int* in_sizes, int n_in,
                              void* d_out, int out_size, void* d_ws, size_t ws_size,
                              hipStream_t stream) {
  const float* x       = (const float*)d_in[0];
  const float* W_in    = (const float*)d_in[1];
  const float* b_in    = (const float*)d_in[2];
  const float* attn_g  = (const float*)d_in[3];
  const float* attn_b  = (const float*)d_in[4];
  const float* Lam_re  = (const float*)d_in[5];
  const float* Lam_im  = (const float*)d_in[6];
  const float* B_re    = (const float*)d_in[7];
  const float* B_im    = (const float*)d_in[8];
  const float* C_re    = (const float*)d_in[9];
  const float* C_im    = (const float*)d_in[10];
  const float* Dv      = (const float*)d_in[11];
  const float* log_step= (const float*)d_in[12];
  const float* ff_g    = (const float*)d_in[13];
  const float* ff_b    = (const float*)d_in[14];
  const float* W_enc   = (const float*)d_in[15];
  const float* W_dec   = (const float*)d_in[16];
  const float* out_g   = (const float*)d_in[17];
  const float* out_b   = (const float*)d_in[18];
  const float* Wc1     = (const float*)d_in[19];
  const float* bc1     = (const float*)d_in[20];
  const float* Wc2     = (const float*)d_in[21];
  const float* bc2     = (const float*)d_in[22];
  float* ws = (float*)d_ws;

  float* hbuf = ws + OFF_H;
  float* A    = ws + OFF_A;
  float* B    = ws + OFF_B;

  k_pre<<<NLAY, 256, 0, stream>>>(Lam_re, Lam_im, B_re, B_im, C_re, C_im, log_step, ws);
  k_inproj<<<dim3(LL/256, BB), 256, 0, stream>>>(x, W_in, b_in, hbuf);

  for (int i=0;i<NLAY;i++){
    const float* pc = ws + OFF_PC + (unsigned long)i*PCS;
    k_bu2<<<ROWS/256, 256, 0, stream>>>(hbuf, pc, attn_g+i*HH, attn_b+i*HH, B);
    k_scanA<<<dim3(NCH,BB), 64, 0, stream>>>(B, pc, ws);
    k_scanB<<<BB, 64, 0, stream>>>(pc, ws);
    k_scanC<<<dim3(NCH,BB), 64, 0, stream>>>(B, A, pc, ws);
    k_ymmgly<<<ROWS/256, 256, 0, stream>>>(B, A, hbuf, pc+16384, Dv+i*HH,
                                           attn_g+i*HH, attn_b+i*HH, ff_g+i*HH, ff_b+i*HH);
    k_enc<<<ROWS/256, 256, 0, stream>>>(B, W_enc + (long)i*HH*2*HH, A);
    k_dec<<<ROWS/128, 128, 0, stream>>>(A, W_dec + (long)i*HH*HH);
    k_ln3<<<ROWS/4, 256, 0, stream>>>(A, B, hbuf, hbuf, out_g+i*HH, out_b+i*HH);
  }
  k_pool<<<dim3(64,BB), 128, 0, stream>>>(hbuf, ws + OFF_EF);
  k_cls<<<1, 256, 0, stream>>>(ws + OFF_EF, Wc1, bc1, Wc2, bc2, (float*)d_out);
}

// Round 4
// 2813.296 us; speedup vs baseline: 5.4244x; 5.4244x over previous
//
#include <hip/hip_runtime.h>
#include <math.h>

#define NLAY 2
#define BB 16
#define LL 8192
#define HH 128
#define PP 64
#define CIN 64
#define CHS 128           // scan chunk size
#define NCH 64            // LL/CHS
#define ROWS (BB*LL)      // 131072

// ---- workspace layout (float offsets) ---- total ~194.4 MiB
#define OFF_H   0ul
#define OFF_A   16777216ul
#define OFF_B   33554432ul
#define OFF_EF  50331648ul            // 8 arrays x 65536 floats (2 MiB); reused for pool partials at end
#define OFF_PC  (OFF_EF + 524288ul)
#define PCS     49408ul               // per-layer: W_bu[16384] W_y[32768] lbar/lch consts

__device__ __forceinline__ float gelu_(float x){
  return 0.5f*x*(1.0f + erff(x*0.70710678118654752440f));
}

// ---- shared macros: stage a 32-col chunk of a [*,128] activation into LDS; write a
// 32-col output chunk back (transpose through LDS). ALL accumulator indexing static. ----
#define STAGE32(SRC, COLBASE) \
  __syncthreads(); \
  _Pragma("unroll") \
  for (int k2=0;k2<32;k2++){ int e = tid + k2*256; int r = e>>5, kk = e&31; \
    s[r*33+kk] = (SRC)[(g0+(long)r)*HH + (COLBASE) + kk]; } \
  __syncthreads();

#define WRITEOUT32(ARR, COLBASE, DST) \
  __syncthreads(); \
  _Pragma("unroll") \
  for (int jj=0;jj<32;jj++) s[tid*33+jj] = ARR[jj]; \
  __syncthreads(); \
  _Pragma("unroll") \
  for (int k2=0;k2<32;k2++){ int e = tid + k2*256; int r = e>>5, jj = e&31; \
    (DST)[(g0+(long)r)*HH + (COLBASE) + jj] = s[r*33+jj]; }

// ---------------- precompute: discretization + packed weight matrices ----------------
__global__ void k_pre(const float* __restrict__ Lam_re, const float* __restrict__ Lam_im,
                      const float* __restrict__ B_re, const float* __restrict__ B_im,
                      const float* __restrict__ C_re, const float* __restrict__ C_im,
                      const float* __restrict__ log_step, float* __restrict__ ws)
{
  int i = blockIdx.x, tid = threadIdx.x;
  float* pc = ws + OFF_PC + (unsigned long)i*PCS;
  __shared__ float qre[PP], qim[PP];
  if (tid < PP){
    int p = tid;
    float lre = Lam_re[i*PP+p], lim = Lam_im[i*PP+p];
    float st = expf(log_step[i*PP+p]);
    float er = expf(lre*st), ang = lim*st;
    float Lr = er*cosf(ang);
    float Li = er*sinf(ang);
    float wr = Lr - 1.0f, wi = Li;
    float den = lre*lre + lim*lim;
    qre[p] = (wr*lre + wi*lim)/den;
    qim[p] = (wi*lre - wr*lim)/den;
    pc[49152+p] = Lr; pc[49216+p] = Li;
    float ec = expf(lre*st*(float)CHS), ac = lim*st*(float)CHS;
    pc[49280+p] = ec*cosf(ac); pc[49344+p] = ec*sinf(ac);
  }
  __syncthreads();
  for (int k = 0; k < 64; k++){
    int e = tid + k*256;
    int h = e>>7, j = e&127, c = j>>6, p = j&63;
    float br = B_re[(i*PP+p)*HH + h], bi = B_im[(i*PP+p)*HH + h];
    pc[e] = c ? (qre[p]*bi + qim[p]*br) : (qre[p]*br - qim[p]*bi);
  }
  for (int k = 0; k < 128; k++){
    int e = tid + k*256;
    int kk = e>>7, h = e&127, c = kk>>6, p = kk&63;
    float v;
    int base = (i*HH + h)*(2*PP);
    if      (c==0) v =  C_re[base + p];
    else if (c==1) v = -C_im[base + p];
    else if (c==2) v =  C_re[base + PP + p];
    else           v = -C_im[base + PP + p];
    pc[16384 + e] = v;
  }
}

// ---------------- input projection: h[b,l,:] = x[b,:,l]^T @ W_in + b_in ----------------
__global__ __launch_bounds__(256,2) void k_inproj(const float* __restrict__ x,
                         const float* __restrict__ W_in,
                         const float* __restrict__ b_in, float* __restrict__ hout)
{
  __shared__ float s[256*33];
  int tid = threadIdx.x;
  int b = blockIdx.y;
  int l0 = blockIdx.x*256;
  long g0 = (long)b*LL + l0;
  float c0[32], c1[32], c2[32], c3[32];
  #pragma unroll
  for (int j=0;j<32;j++){ c0[j]=b_in[j]; c1[j]=b_in[32+j]; c2[j]=b_in[64+j]; c3[j]=b_in[96+j]; }
  #define INP_CHUNK(KC) { \
    __syncthreads(); \
    _Pragma("unroll") \
    for (int k2=0;k2<32;k2++){ \
      s[tid*33+k2] = x[((long)b*CIN + (KC)*32+k2)*LL + l0 + tid]; } \
    __syncthreads(); \
    _Pragma("unroll 2") \
    for (int kk=0;kk<32;kk++){ \
      float a = s[tid*33+kk]; \
      const float* wr = W_in + ((KC)*32+kk)*HH; \
      _Pragma("unroll") \
      for (int j=0;j<32;j++){ c0[j]+=a*wr[j]; c1[j]+=a*wr[32+j]; c2[j]+=a*wr[64+j]; c3[j]+=a*wr[96+j]; } \
    } }
  INP_CHUNK(0) INP_CHUNK(1)
  WRITEOUT32(c0, 0, hout)
  WRITEOUT32(c1, 32, hout)
  WRITEOUT32(c2, 64, hout)
  WRITEOUT32(c3, 96, hout)
}

// ---------------- fused LN1 + Bu matmul: bu[row][re(64)|im(64)] = LN(h) @ W_bu ----------------
__global__ __launch_bounds__(256,2) void k_bu2(const float* __restrict__ h,
                      const float* __restrict__ W,
                      const float* __restrict__ g, const float* __restrict__ bta,
                      float* __restrict__ bu)
{
  __shared__ float s[256*33];
  int tid = threadIdx.x; long g0 = (long)blockIdx.x*256;
  float sum=0.f, sq=0.f;
  for (int kc=0;kc<4;kc++){
    STAGE32(h, kc*32)
    #pragma unroll
    for (int kk=0;kk<32;kk++){ float v = s[tid*33+kk]; sum += v; sq += v*v; }
  }
  float m = sum*(1.0f/HH);
  float inv = 1.0f/sqrtf(sq*(1.0f/HH) - m*m + 1e-5f);
  #define BU_HALF(H0) { \
    float a0[32], a1[32]; \
    _Pragma("unroll") for (int j=0;j<32;j++){ a0[j]=0.f; a1[j]=0.f; } \
    for (int kc=0;kc<4;kc++){ \
      STAGE32(h, kc*32) \
      _Pragma("unroll 2") \
      for (int kk=0;kk<32;kk++){ \
        float fx = (s[tid*33+kk]-m)*inv*g[kc*32+kk] + bta[kc*32+kk]; \
        const float* wr = W + (kc*32+kk)*128 + (H0); \
        _Pragma("unroll") \
        for (int j=0;j<32;j++){ a0[j]+=fx*wr[j]; a1[j]+=fx*wr[32+j]; } \
      } \
    } \
    WRITEOUT32(a0, (H0), bu) \
    WRITEOUT32(a1, (H0)+32, bu) \
  }
  BU_HALF(0)
  BU_HALF(64)
}

// ---------------- scan phase A: per-chunk fwd/bwd reductions ----------------
__global__ void k_scanA(const float* __restrict__ bu, const float* __restrict__ pc,
                        float* __restrict__ ws)
{
  int p = threadIdx.x; int c = blockIdx.x, b = blockIdx.y;
  float Lr = pc[49152+p], Li = pc[49216+p];
  float efr=0.f, efi=0.f, ebr=0.f, ebi=0.f, pwr=1.f, pwi=0.f;
  long base = ((long)b*LL + (long)c*CHS)*HH;
  for (int i=0;i<CHS;i++){
    float br = bu[base + (long)i*HH + p], bi = bu[base + (long)i*HH + 64 + p];
    float nr = Lr*efr - Li*efi + br;
    efi = Lr*efi + Li*efr + bi; efr = nr;
    ebr += pwr*br - pwi*bi;
    ebi += pwr*bi + pwi*br;
    float tr = pwr*Lr - pwi*Li;
    pwi = pwr*Li + pwi*Lr; pwr = tr;
  }
  long o = ((long)b*NCH + c)*PP + p;
  ws[OFF_EF + o] = efr;            ws[OFF_EF+65536 + o] = efi;
  ws[OFF_EF+131072 + o] = ebr;     ws[OFF_EF+196608 + o] = ebi;
}

// ---------------- scan phase B: carry scan over chunks ----------------
__global__ void k_scanB(const float* __restrict__ pc, float* __restrict__ ws)
{
  int p = threadIdx.x; int b = blockIdx.x;
  float Cr = pc[49280+p], Ci = pc[49344+p];
  float Fr=0.f, Fi=0.f;
  for (int c=0;c<NCH;c++){
    long o = ((long)b*NCH + c)*PP + p;
    ws[OFF_EF+262144 + o] = Fr;
    ws[OFF_EF+327680 + o] = Fi;
    float er = ws[OFF_EF + o], ei = ws[OFF_EF+65536 + o];
    float nr = Cr*Fr - Ci*Fi + er;
    Fi = Cr*Fi + Ci*Fr + ei; Fr = nr;
  }
  float Xr=0.f, Xi=0.f;
  for (int c=NCH-1;c>=0;c--){
    long o = ((long)b*NCH + c)*PP + p;
    ws[OFF_EF+393216 + o] = Xr;
    ws[OFF_EF+458752 + o] = Xi;
    float er = ws[OFF_EF+131072 + o], ei = ws[OFF_EF+196608 + o];
    float nr = er + Cr*Xr - Ci*Xi;
    Xi = ei + Cr*Xi + Ci*Xr; Xr = nr;
  }
}

// ---------------- scan phase C: xf in-place over bu; xb -> A ----------------
__global__ void k_scanC(float* __restrict__ bu, float* __restrict__ xb,
                        const float* __restrict__ pc, const float* __restrict__ wsc)
{
  __shared__ float sbr[CHS*PP], sbi[CHS*PP];
  int p = threadIdx.x; int c = blockIdx.x, b = blockIdx.y;
  float Lr = pc[49152+p], Li = pc[49216+p];
  long o = ((long)b*NCH + c)*PP + p;
  float xr = wsc[OFF_EF+262144 + o], xi = wsc[OFF_EF+327680 + o];
  long base = ((long)b*LL + (long)c*CHS)*HH;
  for (int i=0;i<CHS;i++){
    long a0 = base + (long)i*HH;
    float br = bu[a0+p], bi = bu[a0+64+p];
    sbr[i*PP+p] = br; sbi[i*PP+p] = bi;
    float nr = Lr*xr - Li*xi + br;
    xi = Lr*xi + Li*xr + bi; xr = nr;
    bu[a0+p] = xr; bu[a0+64+p] = xi;
  }
  float yr = wsc[OFF_EF+393216 + o], yi = wsc[OFF_EF+458752 + o];
  for (int i=CHS-1;i>=0;i--){
    long a0 = base + (long)i*HH;
    float br = sbr[i*PP+p], bi = sbi[i*PP+p];
    float nr = Lr*yr - Li*yi + br;
    yi = Lr*yi + Li*yr + bi; yr = nr;
    xb[a0+p] = yr; xb[a0+64+p] = yi;
  }
}

// ---------------- fused y-matmul + D*fx + gelu + residual + LN2 -> fy (in-place over xf) ----------------
__global__ __launch_bounds__(256,2) void k_ymmgly(float* __restrict__ xf,
                         const float* __restrict__ xb,
                         const float* __restrict__ h, const float* __restrict__ Wy,
                         const float* __restrict__ Dv,
                         const float* __restrict__ ag, const float* __restrict__ ab,
                         const float* __restrict__ fg, const float* __restrict__ fb)
{
  __shared__ float s[256*33];
  int tid = threadIdx.x; long g0 = (long)blockIdx.x*256;
  // LN1 stats from h
  float sum=0.f, sq=0.f;
  for (int kc=0;kc<4;kc++){
    STAGE32(h, kc*32)
    #pragma unroll
    for (int kk=0;kk<32;kk++){ float v = s[tid*33+kk]; sum += v; sq += v*v; }
  }
  float m1 = sum*(1.0f/HH);
  float inv1 = 1.0f/sqrtf(sq*(1.0f/HH) - m1*m1 + 1e-5f);
  // y = xs @ W_y  (K=256)
  float c0[32], c1[32], c2[32], c3[32];
  #pragma unroll
  for (int j=0;j<32;j++){ c0[j]=0.f; c1[j]=0.f; c2[j]=0.f; c3[j]=0.f; }
  #define YMM_CHUNK(Q, SRC) { \
    STAGE32(SRC, ((Q)&3)*32) \
    _Pragma("unroll 2") \
    for (int kk=0;kk<32;kk++){ \
      float a = s[tid*33+kk]; \
      const float* wr = Wy + ((Q)*32+kk)*128; \
      _Pragma("unroll") \
      for (int j=0;j<32;j++){ c0[j]+=a*wr[j]; c1[j]+=a*wr[32+j]; c2[j]+=a*wr[64+j]; c3[j]+=a*wr[96+j]; } \
    } }
  YMM_CHUNK(0,xf) YMM_CHUNK(1,xf) YMM_CHUNK(2,xf) YMM_CHUNK(3,xf)
  YMM_CHUNK(4,xb) YMM_CHUNK(5,xb) YMM_CHUNK(6,xb) YMM_CHUNK(7,xb)
  // a = gelu(y + D*fx) + fx ; then LN2 -> fy
  float sum2=0.f, sq2=0.f;
  #define GELU_CHUNK(KC, CARR) { \
    STAGE32(h, (KC)*32) \
    _Pragma("unroll") \
    for (int kk=0;kk<32;kk++){ int j=(KC)*32+kk; \
      float fxv = (s[tid*33+kk]-m1)*inv1*ag[j] + ab[j]; \
      float av = gelu_(CARR[kk] + Dv[j]*fxv) + fxv; \
      CARR[kk] = av; sum2 += av; sq2 += av*av; } }
  GELU_CHUNK(0,c0) GELU_CHUNK(1,c1) GELU_CHUNK(2,c2) GELU_CHUNK(3,c3)
  float m2 = sum2*(1.0f/HH);
  float inv2 = 1.0f/sqrtf(sq2*(1.0f/HH) - m2*m2 + 1e-5f);
  #pragma unroll
  for (int j=0;j<32;j++){
    c0[j] = (c0[j]-m2)*inv2*fg[j]    + fb[j];
    c1[j] = (c1[j]-m2)*inv2*fg[32+j] + fb[32+j];
    c2[j] = (c2[j]-m2)*inv2*fg[64+j] + fb[64+j];
    c3[j] = (c3[j]-m2)*inv2*fg[96+j] + fb[96+j];
  }
  WRITEOUT32(c0, 0, xf)
  WRITEOUT32(c1, 32, xf)
  WRITEOUT32(c2, 64, xf)
  WRITEOUT32(c3, 96, xf)
}

// ---------------- GEGLU encode: t = v * gelu(g),  e = fy @ W_enc ----------------
__global__ __launch_bounds__(256,2) void k_enc(const float* __restrict__ act,
                      const float* __restrict__ Wenc,
                      float* __restrict__ tout)
{
  __shared__ float s[256*33];
  int tid = threadIdx.x; long g0 = (long)blockIdx.x*256;
  #define ENC_HALF(H0) { \
    float v0[32], v1[32], ga[32], gb[32]; \
    _Pragma("unroll") for (int j=0;j<32;j++){ v0[j]=0.f; v1[j]=0.f; ga[j]=0.f; gb[j]=0.f; } \
    for (int kc=0;kc<4;kc++){ \
      STAGE32(act, kc*32) \
      _Pragma("unroll 2") \
      for (int kk=0;kk<32;kk++){ \
        float a = s[tid*33+kk]; \
        const float* wv = Wenc + (kc*32+kk)*256 + (H0); \
        const float* wg = wv + 128; \
        _Pragma("unroll") \
        for (int j=0;j<32;j++){ v0[j]+=a*wv[j]; v1[j]+=a*wv[32+j]; ga[j]+=a*wg[j]; gb[j]+=a*wg[32+j]; } \
      } \
    } \
    _Pragma("unroll") \
    for (int j=0;j<32;j++){ v0[j] *= gelu_(ga[j]); v1[j] *= gelu_(gb[j]); } \
    WRITEOUT32(v0, (H0), tout) \
    WRITEOUT32(v1, (H0)+32, tout) \
  }
  ENC_HALF(0)
  ENC_HALF(64)
}

// ---------------- decode in-place: blk = t @ W_dec over the t buffer ----------------
// 256 threads, 128 rows staged in 64KB swizzled LDS; thread owns 64 cols of one row.
__global__ __launch_bounds__(256,2) void k_dec(float* __restrict__ tb, const float* __restrict__ W)
{
  __shared__ float s[128*128];
  int tid = threadIdx.x; long g0 = (long)blockIdx.x*128;
  #pragma unroll
  for (int it=0; it<64; it++){
    int e = tid + it*256; int r = e>>7, cc = e&127;
    s[r*128 + (cc ^ (r&31))] = tb[(g0+r)*HH + cc];
  }
  __syncthreads();
  int row = tid & 127, ch = tid >> 7;
  float a0[32], a1[32];
  #pragma unroll
  for (int j=0;j<32;j++){ a0[j]=0.f; a1[j]=0.f; }
  #pragma unroll 2
  for (int k=0;k<128;k++){
    float a = s[row*128 + (k ^ (row&31))];
    const float* wr = W + k*128 + ch*64;
    #pragma unroll
    for (int j=0;j<32;j++){ a0[j]+=a*wr[j]; a1[j]+=a*wr[32+j]; }
  }
  __syncthreads();
  #pragma unroll
  for (int j=0;j<32;j++){
    s[row*128 + ((ch*64+j)    ^ (row&31))] = a0[j];
    s[row*128 + ((ch*64+32+j) ^ (row&31))] = a1[j];
  }
  __syncthreads();
  #pragma unroll
  for (int it=0; it<64; it++){
    int e = tid + it*256; int r = e>>7, cc = e&127;
    tb[(g0+r)*HH + cc] = s[r*128 + (cc ^ (r&31))];
  }
}

// ---------------- blk + fy + res -> LN -> dst ----------------
__global__ void k_ln3(const float* __restrict__ blk, const float* __restrict__ fy,
                      const float* __restrict__ res, float* __restrict__ dst,
                      const float* __restrict__ g, const float* __restrict__ bta)
{
  int wv = threadIdx.x>>6, lane = threadIdx.x&63;
  long row = (long)blockIdx.x*4 + wv;
  long o = row*HH;
  float a0 = blk[o+lane]    + fy[o+lane]    + res[o+lane];
  float a1 = blk[o+lane+64] + fy[o+lane+64] + res[o+lane+64];
  float sum = a0+a1, sq = a0*a0+a1*a1;
  #pragma unroll
  for (int oo=1;oo<64;oo<<=1){ sum += __shfl_xor(sum,oo); sq += __shfl_xor(sq,oo); }
  float m = sum*(1.0f/HH);
  float var = sq*(1.0f/HH) - m*m;
  float inv = 1.0f/sqrtf(var + 1e-5f);
  dst[o+lane]    = (a0-m)*inv*g[lane]    + bta[lane];
  dst[o+lane+64] = (a1-m)*inv*g[lane+64] + bta[lane+64];
}

// ---------------- mean pool partials ----------------
__global__ void k_pool(const float* __restrict__ hbuf, float* __restrict__ part)
{
  int h = threadIdx.x; int seg = blockIdx.x, b = blockIdx.y;
  float sum=0.f;
  long base = ((long)b*LL + (long)seg*128)*HH + h;
  for (int i=0;i<128;i++) sum += hbuf[base + (long)i*HH];
  part[((long)seg*BB + b)*HH + h] = sum;
}

// ---------------- classifier head (fp32 output) ----------------
__global__ void k_cls(const float* __restrict__ part, const float* __restrict__ Wc1,
                      const float* __restrict__ bc1, const float* __restrict__ Wc2,
                      const float* __restrict__ bc2, float* __restrict__ out)
{
  __shared__ float pooled[BB*HH];
  __shared__ float zs[BB*64];
  int tid = threadIdx.x;
  for (int k=0;k<8;k++){
    int e = tid + k*256; int b = e>>7, hh = e&127;
    float s = 0.f;
    for (int seg=0; seg<64; seg++) s += part[((long)seg*BB + b)*HH + hh];
    pooled[e] = s * (1.0f/(float)LL);
  }
  __syncthreads();
  for (int k=0;k<4;k++){
    int e = tid + k*256; int b = e>>6, j = e&63;
    float s = bc1[j];
    for (int hh=0; hh<HH; hh++) s += pooled[b*HH+hh]*Wc1[hh*64+j];
    zs[e] = fmaxf(s, 0.0f);
  }
  __syncthreads();
  if (tid < BB*3){
    int b = tid/3, cc = tid%3;
    float s = bc2[cc];
    for (int j=0;j<64;j++) s += zs[b*64+j]*Wc2[j*3+cc];
    out[tid] = s;
  }
}

extern "C" void kernel_launch(void* const* d_in, const int* in_sizes, int n_in,
                              void* d_out, int out_size, void* d_ws, size_t ws_size,
                              hipStream_t stream) {
  const float* x       = (const float*)d_in[0];
  const float* W_in    = (const float*)d_in[1];
  const float* b_in    = (const float*)d_in[2];
  const float* attn_g  = (const float*)d_in[3];
  const float* attn_b  = (const float*)d_in[4];
  const float* Lam_re  = (const float*)d_in[5];
  const float* Lam_im  = (const float*)d_in[6];
  const float* B_re    = (const float*)d_in[7];
  const float* B_im    = (const float*)d_in[8];
  const float* C_re    = (const float*)d_in[9];
  const float* C_im    = (const float*)d_in[10];
  const float* Dv      = (const float*)d_in[11];
  const float* log_step= (const float*)d_in[12];
  const float* ff_g    = (const float*)d_in[13];
  const float* ff_b    = (const float*)d_in[14];
  const float* W_enc   = (const float*)d_in[15];
  const float* W_dec   = (const float*)d_in[16];
  const float* out_g   = (const float*)d_in[17];
  const float* out_b   = (const float*)d_in[18];
  const float* Wc1     = (const float*)d_in[19];
  const float* bc1     = (const float*)d_in[20];
  const float* Wc2     = (const float*)d_in[21];
  const float* bc2     = (const float*)d_in[22];
  float* ws = (float*)d_ws;

  float* hbuf = ws + OFF_H;
  float* A    = ws + OFF_A;
  float* B    = ws + OFF_B;

  k_pre<<<NLAY, 256, 0, stream>>>(Lam_re, Lam_im, B_re, B_im, C_re, C_im, log_step, ws);
  k_inproj<<<dim3(LL/256, BB), 256, 0, stream>>>(x, W_in, b_in, hbuf);

  for (int i=0;i<NLAY;i++){
    const float* pc = ws + OFF_PC + (unsigned long)i*PCS;
    k_bu2<<<ROWS/256, 256, 0, stream>>>(hbuf, pc, attn_g+i*HH, attn_b+i*HH, B);
    k_scanA<<<dim3(NCH,BB), 64, 0, stream>>>(B, pc, ws);
    k_scanB<<<BB, 64, 0, stream>>>(pc, ws);
    k_scanC<<<dim3(NCH,BB), 64, 0, stream>>>(B, A, pc, ws);
    k_ymmgly<<<ROWS/256, 256, 0, stream>>>(B, A, hbuf, pc+16384, Dv+i*HH,
                                           attn_g+i*HH, attn_b+i*HH, ff_g+i*HH, ff_b+i*HH);
    k_enc<<<ROWS/256, 256, 0, stream>>>(B, W_enc + (long)i*HH*2*HH, A);
    k_dec<<<ROWS/128, 256, 0, stream>>>(A, W_dec + (long)i*HH*HH);
    k_ln3<<<ROWS/4, 256, 0, stream>>>(A, B, hbuf, hbuf, out_g+i*HH, out_b+i*HH);
  }
  k_pool<<<dim3(64,BB), 128, 0, stream>>>(hbuf, ws + OFF_EF);
  k_cls<<<1, 256, 0, stream>>>(ws + OFF_EF, Wc1, bc1, Wc2, bc2, (float*)d_out);
}

// Round 5
// 707.786 us; speedup vs baseline: 21.5609x; 3.9748x over previous
//
#include <hip/hip_runtime.h>
#include <math.h>

#define NLAY 2
#define BB 16
#define LL 8192
#define HH 128
#define PP 64
#define CIN 64
#define CHS 64            // scan chunk size
#define NCH 128           // LL/CHS
#define ROWS (BB*LL)      // 131072

typedef unsigned short u16;
typedef __attribute__((ext_vector_type(8))) short  bf16x8;
typedef __attribute__((ext_vector_type(4))) float  f32x4;

// ---- workspace layout (float offsets) ---- total ~196.4 MiB
#define OFF_H   0ul               // h fp32 [ROWS][128]
#define OFF_FX  16777216ul        // fx bf16 [ROWS][128] (8.4M floats)
#define OFF_XF  25165824ul        // xf bf16 -> later fy bf16
#define OFF_XB  33554432ul        // xb bf16 -> later t bf16
#define OFF_BU  41943040ul        // bu bf16
#define OFF_EF  50331648ul        // 8 carry arrays x 131072 floats (4 MiB); pool partials reuse
#define OFF_PC  51380224ul
#define PCS     49408ul           // per-layer: packs 49152 floats (98304 bf16) + 256 consts
#define EFS     131072ul

__device__ __forceinline__ float gelu_(float x){
  return 0.5f*x*(1.0f + erff(x*0.70710678118654752440f));
}
__device__ __forceinline__ u16 f2bf(float f){
  unsigned int u = __float_as_uint(f);
  return (u16)((u + 0x7fffu + ((u>>16)&1u)) >> 16);
}
__device__ __forceinline__ float bf2f(u16 v){
  return __uint_as_float(((unsigned int)v)<<16);
}

// ================= precompute: discretization + MFMA-fragment weight packs =================
// pack layout (bf16 units from pb): bu @0 (16384), y @16384 (32768), enc @49152 (32768), dec @81920 (16384)
// fragment: pack[((ct*KS + ks)*64 + lane)*8 + j] = Wt[col = ct*16 + (lane&15)][k = ks*32 + (lane>>4)*8 + j]
__global__ void k_pre(const float* __restrict__ Lam_re, const float* __restrict__ Lam_im,
                      const float* __restrict__ B_re, const float* __restrict__ B_im,
                      const float* __restrict__ C_re, const float* __restrict__ C_im,
                      const float* __restrict__ W_enc, const float* __restrict__ W_dec,
                      const float* __restrict__ log_step, float* __restrict__ ws)
{
  int i = blockIdx.x, tid = threadIdx.x;
  float* pcf = ws + OFF_PC + (unsigned long)i*PCS;
  u16* pb = (u16*)pcf;
  float* cons = pcf + 49152;
  __shared__ float qre[PP], qim[PP];
  if (tid < PP){
    int p = tid;
    float lre = Lam_re[i*PP+p], lim = Lam_im[i*PP+p];
    float st = expf(log_step[i*PP+p]);
    float er = expf(lre*st), ang = lim*st;
    float Lr = er*cosf(ang), Li = er*sinf(ang);
    float wr = Lr - 1.0f, wi = Li;
    float den = lre*lre + lim*lim;
    qre[p] = (wr*lre + wi*lim)/den;
    qim[p] = (wi*lre - wr*lim)/den;
    cons[p] = Lr; cons[64+p] = Li;
    float ec = expf(lre*st*(float)CHS), ac = lim*st*(float)CHS;
    cons[128+p] = ec*cosf(ac); cons[192+p] = ec*sinf(ac);
  }
  __syncthreads();
  // bu pack: Wt[col][k]: col=c*64+p over [re|im], k=h.  Bbar = q*(B_re + i B_im)
  for (int t0 = tid; t0 < 16384; t0 += 256){
    int j = t0&7, ln = (t0>>3)&63, ks = (t0>>9)&3, ct = t0>>11;
    int col = ct*16 + (ln&15);
    int k = ks*32 + (ln>>4)*8 + j;
    int cc = col>>6, p = col&63;
    float br = B_re[(i*PP+p)*HH + k], bi = B_im[(i*PP+p)*HH + k];
    pb[t0] = f2bf(cc ? (qre[p]*bi + qim[p]*br) : (qre[p]*br - qim[p]*bi));
  }
  // y pack: Wt[h][k], k: 0-63 xf_re->Cre[h][p]; 64-127 xf_im->-Cim[h][p]; 128-191 xb_re->Cre[h][64+p]; 192-255 xb_im->-Cim[h][64+p]
  for (int t0 = tid; t0 < 32768; t0 += 256){
    int j = t0&7, ln = (t0>>3)&63, ks = (t0>>9)&7, ct = t0>>12;
    int hh = ct*16 + (ln&15);
    int k = ks*32 + (ln>>4)*8 + j;
    int blk = k>>6, p = k&63;
    int base = (i*HH + hh)*(2*PP);
    float v = (blk==0)? C_re[base+p] : (blk==1)? -C_im[base+p]
            : (blk==2)? C_re[base+PP+p] : -C_im[base+PP+p];
    pb[16384 + t0] = f2bf(v);
  }
  // enc pack: Wt[j][k] = W_enc[k][j]; ct<8 -> v cols (j=ct*16+c), ct>=8 -> g cols (j=128+(ct-8)*16+c)
  for (int t0 = tid; t0 < 32768; t0 += 256){
    int j = t0&7, ln = (t0>>3)&63, ks = (t0>>9)&3, ct = t0>>11;
    int colj = (ct<8) ? ct*16 + (ln&15) : 128 + (ct-8)*16 + (ln&15);
    int k = ks*32 + (ln>>4)*8 + j;
    pb[49152 + t0] = f2bf(W_enc[((long)i*HH + k)*(2*HH) + colj]);
  }
  // dec pack
  for (int t0 = tid; t0 < 16384; t0 += 256){
    int j = t0&7, ln = (t0>>3)&63, ks = (t0>>9)&3, ct = t0>>11;
    int col = ct*16 + (ln&15);
    int k = ks*32 + (ln>>4)*8 + j;
    pb[81920 + t0] = f2bf(W_dec[((long)i*HH + k)*HH + col]);
  }
}

// ================= input projection (fp32 VALU, unchanged) =================
#define WRITEOUT32(ARR, COLBASE, DST) \
  __syncthreads(); \
  _Pragma("unroll") \
  for (int jj=0;jj<32;jj++) s[tid*33+jj] = ARR[jj]; \
  __syncthreads(); \
  _Pragma("unroll") \
  for (int k2=0;k2<32;k2++){ int e = tid + k2*256; int r = e>>5, jj = e&31; \
    (DST)[(g0+(long)r)*HH + (COLBASE) + jj] = s[r*33+jj]; }

__global__ __launch_bounds__(256,2) void k_inproj(const float* __restrict__ x,
                         const float* __restrict__ W_in,
                         const float* __restrict__ b_in, float* __restrict__ hout)
{
  __shared__ float s[256*33];
  int tid = threadIdx.x;
  int b = blockIdx.y;
  int l0 = blockIdx.x*256;
  long g0 = (long)b*LL + l0;
  float c0[32], c1[32], c2[32], c3[32];
  #pragma unroll
  for (int j=0;j<32;j++){ c0[j]=b_in[j]; c1[j]=b_in[32+j]; c2[j]=b_in[64+j]; c3[j]=b_in[96+j]; }
  #define INP_CHUNK(KC) { \
    __syncthreads(); \
    _Pragma("unroll") \
    for (int k2=0;k2<32;k2++){ \
      s[tid*33+k2] = x[((long)b*CIN + (KC)*32+k2)*LL + l0 + tid]; } \
    __syncthreads(); \
    _Pragma("unroll 2") \
    for (int kk=0;kk<32;kk++){ \
      float a = s[tid*33+kk]; \
      const float* wr = W_in + ((KC)*32+kk)*HH; \
      _Pragma("unroll") \
      for (int j=0;j<32;j++){ c0[j]+=a*wr[j]; c1[j]+=a*wr[32+j]; c2[j]+=a*wr[64+j]; c3[j]+=a*wr[96+j]; } \
    } }
  INP_CHUNK(0) INP_CHUNK(1)
  WRITEOUT32(c0, 0, hout)
  WRITEOUT32(c1, 32, hout)
  WRITEOUT32(c2, 64, hout)
  WRITEOUT32(c3, 96, hout)
}

// ================= LN1: h fp32 -> fx bf16 =================
__global__ void k_ln1(const float* __restrict__ src, u16* __restrict__ dst,
                      const float* __restrict__ g, const float* __restrict__ bta)
{
  int wv = threadIdx.x>>6, lane = threadIdx.x&63;
  long row = (long)blockIdx.x*4 + wv;
  long o = row*HH;
  float a0 = src[o+lane], a1 = src[o+lane+64];
  float sum = a0+a1, sq = a0*a0+a1*a1;
  #pragma unroll
  for (int of=1;of<64;of<<=1){ sum += __shfl_xor(sum,of); sq += __shfl_xor(sq,of); }
  float m = sum*(1.0f/HH);
  float inv = 1.0f/sqrtf(sq*(1.0f/HH) - m*m + 1e-5f);
  dst[o+lane]    = f2bf((a0-m)*inv*g[lane]    + bta[lane]);
  dst[o+lane+64] = f2bf((a1-m)*inv*g[lane+64] + bta[lane+64]);
}

// ================= GEMM skeleton macros =================
// 256 threads = 4 waves; 128 rows/block; wave w -> rows [w*32, w*32+32); 8 col-tiles of 16.
// LDS A tile [128][136] bf16 (pad 8 -> conflict-balanced b128 reads).
#define GEMM_PRE \
  __shared__ u16 sA[128*136]; \
  int tid = threadIdx.x; long g0 = (long)blockIdx.x*128; \
  int lane = tid & 63, wid = tid >> 6; \
  int g = lane >> 4, c = lane & 15; \
  int R0 = wid*32; (void)g; (void)c; (void)R0;

#define STAGE_BF(SRC) do{ __syncthreads(); \
  _Pragma("unroll") \
  for (int rep=0; rep<8; rep++){ int e = tid + rep*256; \
    int r = e>>4, c8 = (e&15)*8; \
    *(bf16x8*)&sA[r*136 + c8] = *(const bf16x8*)((SRC) + (g0 + r)*HH + c8); } \
  __syncthreads(); }while(0)

#define MAINLOOP8(PACK, KSTOT, KSOFF) do{ \
  _Pragma("unroll") \
  for (int ks=0; ks<4; ks++){ \
    bf16x8 a0 = *(const bf16x8*)&sA[(R0 + c)*136 + ks*32 + g*8]; \
    bf16x8 a1 = *(const bf16x8*)&sA[(R0 + 16 + c)*136 + ks*32 + g*8]; \
    _Pragma("unroll") \
    for (int ct=0; ct<8; ct++){ \
      bf16x8 b = ((const bf16x8*)(PACK))[(ct*(KSTOT) + (KSOFF) + ks)*64 + lane]; \
      acc0[ct] = __builtin_amdgcn_mfma_f32_16x16x32_bf16(a0, b, acc0[ct], 0,0,0); \
      acc1[ct] = __builtin_amdgcn_mfma_f32_16x16x32_bf16(a1, b, acc1[ct], 0,0,0); } } }while(0)

#define ACC_ZERO \
  f32x4 acc0[8], acc1[8]; \
  { f32x4 z = {0.f,0.f,0.f,0.f}; \
    _Pragma("unroll") for (int ct=0; ct<8; ct++){ acc0[ct]=z; acc1[ct]=z; } }

// ================= bu = fx @ W_bu (bf16 out) =================
__global__ __launch_bounds__(256,2) void k_gemm_bu(const u16* __restrict__ fxb,
                      const u16* __restrict__ pack, u16* __restrict__ bub)
{
  GEMM_PRE
  ACC_ZERO
  STAGE_BF(fxb);
  MAINLOOP8(pack, 4, 0);
  #define BUST(ACCA, RT) \
    _Pragma("unroll") for (int ct=0; ct<8; ct++){ int col = ct*16 + c; \
      _Pragma("unroll") for (int q=0;q<4;q++){ \
        int rowL = R0 + (RT)*16 + g*4 + q; \
        bub[(g0+rowL)*HH + col] = f2bf(ACCA[ct][q]); } }
  BUST(acc0, 0)
  BUST(acc1, 1)
}

// ================= scan A: per-chunk fwd/bwd reductions (bu bf16 in) =================
__global__ void k_scanA(const u16* __restrict__ bub, const float* __restrict__ cons,
                        float* __restrict__ ws)
{
  int p = threadIdx.x; int ch = blockIdx.x, b = blockIdx.y;
  float Lr = cons[p], Li = cons[64+p];
  float efr=0.f, efi=0.f, ebr=0.f, ebi=0.f, pwr=1.f, pwi=0.f;
  long base = ((long)b*LL + (long)ch*CHS)*HH;
  for (int i=0;i<CHS;i++){
    float br = bf2f(bub[base + (long)i*HH + p]);
    float bi = bf2f(bub[base + (long)i*HH + 64 + p]);
    float nr = Lr*efr - Li*efi + br;
    efi = Lr*efi + Li*efr + bi; efr = nr;
    ebr += pwr*br - pwi*bi;
    ebi += pwr*bi + pwi*br;
    float tr = pwr*Lr - pwi*Li;
    pwi = pwr*Li + pwi*Lr; pwr = tr;
  }
  long o = ((long)b*NCH + ch)*PP + p;
  ws[OFF_EF + o]       = efr;  ws[OFF_EF+EFS + o]   = efi;
  ws[OFF_EF+2*EFS + o] = ebr;  ws[OFF_EF+3*EFS + o] = ebi;
}

// ================= scan B: carry scan over chunks =================
__global__ void k_scanB(const float* __restrict__ cons, float* __restrict__ ws)
{
  int p = threadIdx.x; int b = blockIdx.x;
  float Cr = cons[128+p], Ci = cons[192+p];
  float Fr=0.f, Fi=0.f;
  for (int ch=0;ch<NCH;ch++){
    long o = ((long)b*NCH + ch)*PP + p;
    ws[OFF_EF+4*EFS + o] = Fr;
    ws[OFF_EF+5*EFS + o] = Fi;
    float er = ws[OFF_EF + o], ei = ws[OFF_EF+EFS + o];
    float nr = Cr*Fr - Ci*Fi + er;
    Fi = Cr*Fi + Ci*Fr + ei; Fr = nr;
  }
  float Xr=0.f, Xi=0.f;
  for (int ch=NCH-1;ch>=0;ch--){
    long o = ((long)b*NCH + ch)*PP + p;
    ws[OFF_EF+6*EFS + o] = Xr;
    ws[OFF_EF+7*EFS + o] = Xi;
    float er = ws[OFF_EF+2*EFS + o], ei = ws[OFF_EF+3*EFS + o];
    float nr = er + Cr*Xr - Ci*Xi;
    Xi = ei + Cr*Xi + Ci*Xr; Xr = nr;
  }
}

// ================= scan C: final inclusive scans; bf16 xf/xb out; re-reads bu (L2/L3 hot) =================
__global__ void k_scanC(const u16* __restrict__ bub, u16* __restrict__ xfb,
                        u16* __restrict__ xbb, const float* __restrict__ cons,
                        const float* __restrict__ wsc)
{
  int p = threadIdx.x; int ch = blockIdx.x, b = blockIdx.y;
  float Lr = cons[p], Li = cons[64+p];
  long o = ((long)b*NCH + ch)*PP + p;
  float xr = wsc[OFF_EF+4*EFS + o], xi = wsc[OFF_EF+5*EFS + o];
  long base = ((long)b*LL + (long)ch*CHS)*HH;
  for (int i=0;i<CHS;i++){
    long a0 = base + (long)i*HH;
    float br = bf2f(bub[a0+p]), bi = bf2f(bub[a0+64+p]);
    float nr = Lr*xr - Li*xi + br;
    xi = Lr*xi + Li*xr + bi; xr = nr;
    xfb[a0+p] = f2bf(xr); xfb[a0+64+p] = f2bf(xi);
  }
  float yr = wsc[OFF_EF+6*EFS + o], yi = wsc[OFF_EF+7*EFS + o];
  for (int i=CHS-1;i>=0;i--){
    long a0 = base + (long)i*HH;
    float br = bf2f(bub[a0+p]), bi = bf2f(bub[a0+64+p]);
    float nr = Lr*yr - Li*yi + br;
    yi = Lr*yi + Li*yr + bi; yr = nr;
    xbb[a0+p] = f2bf(yr); xbb[a0+64+p] = f2bf(yi);
  }
}

// ================= y = xs @ W_y ; a = gelu(y + D*fx) + fx ; fy = LN2(a) -> bf16 (over xf) =================
__global__ __launch_bounds__(256,2) void k_gemm_y(u16* __restrict__ xfb,
                      const u16* __restrict__ xbb, const u16* __restrict__ fxb,
                      const u16* __restrict__ pack, const float* __restrict__ Dv,
                      const float* __restrict__ fg, const float* __restrict__ fb)
{
  GEMM_PRE
  ACC_ZERO
  STAGE_BF(xfb);
  MAINLOOP8(pack, 8, 0);
  STAGE_BF(xbb);
  MAINLOOP8(pack, 8, 4);
  // epilogue: a = gelu(y + D*fx) + fx
  #define YEPI(ACCA, RT) \
    _Pragma("unroll") for (int ct=0; ct<8; ct++){ int col = ct*16 + c; \
      float dvc = Dv[col]; \
      _Pragma("unroll") for (int q=0;q<4;q++){ \
        int rowL = R0 + (RT)*16 + g*4 + q; \
        float fxv = bf2f(fxb[(g0+rowL)*HH + col]); \
        ACCA[ct][q] = gelu_(ACCA[ct][q] + dvc*fxv) + fxv; } }
  YEPI(acc0, 0)
  YEPI(acc1, 1)
  // LN2 per row (16-lane shfl groups) + store bf16 fy
  #define YLN(ACCA, RT) \
    _Pragma("unroll") for (int q=0;q<4;q++){ \
      float sm=0.f, sq=0.f; \
      _Pragma("unroll") for (int ct=0;ct<8;ct++){ float v=ACCA[ct][q]; sm+=v; sq+=v*v; } \
      sm += __shfl_xor(sm,1); sq += __shfl_xor(sq,1); \
      sm += __shfl_xor(sm,2); sq += __shfl_xor(sq,2); \
      sm += __shfl_xor(sm,4); sq += __shfl_xor(sq,4); \
      sm += __shfl_xor(sm,8); sq += __shfl_xor(sq,8); \
      float m = sm*(1.0f/HH); \
      float inv = 1.0f/sqrtf(sq*(1.0f/HH) - m*m + 1e-5f); \
      int rowL = R0 + (RT)*16 + g*4 + q; \
      _Pragma("unroll") for (int ct=0;ct<8;ct++){ int col = ct*16 + c; \
        xfb[(g0+rowL)*HH + col] = f2bf((ACCA[ct][q]-m)*inv*fg[col] + fb[col]); } }
  YLN(acc0, 0)
  YLN(acc1, 1)
}

// ================= GEGLU encode: t = v * gelu(gt), [v|gt] = fy @ W_enc =================
__global__ __launch_bounds__(256,2) void k_gemm_enc(const u16* __restrict__ fyb,
                      const u16* __restrict__ pack, u16* __restrict__ tb)
{
  GEMM_PRE
  f32x4 av0[8], av1[8], ag0[8], ag1[8];
  { f32x4 z = {0.f,0.f,0.f,0.f};
    #pragma unroll
    for (int ct=0; ct<8; ct++){ av0[ct]=z; av1[ct]=z; ag0[ct]=z; ag1[ct]=z; } }
  STAGE_BF(fyb);
  #pragma unroll
  for (int ks=0; ks<4; ks++){
    bf16x8 a0 = *(const bf16x8*)&sA[(R0 + c)*136 + ks*32 + g*8];
    bf16x8 a1 = *(const bf16x8*)&sA[(R0 + 16 + c)*136 + ks*32 + g*8];
    #pragma unroll
    for (int ct=0; ct<8; ct++){
      bf16x8 bv = ((const bf16x8*)pack)[(ct*4 + ks)*64 + lane];
      av0[ct] = __builtin_amdgcn_mfma_f32_16x16x32_bf16(a0, bv, av0[ct], 0,0,0);
      av1[ct] = __builtin_amdgcn_mfma_f32_16x16x32_bf16(a1, bv, av1[ct], 0,0,0);
      bf16x8 bg = ((const bf16x8*)pack)[((ct+8)*4 + ks)*64 + lane];
      ag0[ct] = __builtin_amdgcn_mfma_f32_16x16x32_bf16(a0, bg, ag0[ct], 0,0,0);
      ag1[ct] = __builtin_amdgcn_mfma_f32_16x16x32_bf16(a1, bg, ag1[ct], 0,0,0);
    }
  }
  #define ENCST(VA, GA, RT) \
    _Pragma("unroll") for (int ct=0; ct<8; ct++){ int col = ct*16 + c; \
      _Pragma("unroll") for (int q=0;q<4;q++){ \
        int rowL = R0 + (RT)*16 + g*4 + q; \
        tb[(g0+rowL)*HH + col] = f2bf(VA[ct][q] * gelu_(GA[ct][q])); } }
  ENCST(av0, ag0, 0)
  ENCST(av1, ag1, 1)
}

// ================= decode + residual + LN3: h = LN(t@W_dec + fy + h) =================
__global__ __launch_bounds__(256,2) void k_gemm_dec(const u16* __restrict__ tb,
                      const u16* __restrict__ fyb, float* __restrict__ h,
                      const u16* __restrict__ pack,
                      const float* __restrict__ og, const float* __restrict__ ob)
{
  GEMM_PRE
  ACC_ZERO
  STAGE_BF(tb);
  MAINLOOP8(pack, 4, 0);
  // add fy + residual h
  #define DADD(ACCA, RT) \
    _Pragma("unroll") for (int ct=0; ct<8; ct++){ int col = ct*16 + c; \
      _Pragma("unroll") for (int q=0;q<4;q++){ \
        int rowL = R0 + (RT)*16 + g*4 + q; long ix = (g0+rowL)*HH + col; \
        ACCA[ct][q] += bf2f(fyb[ix]) + h[ix]; } }
  DADD(acc0, 0)
  DADD(acc1, 1)
  #define DLN(ACCA, RT) \
    _Pragma("unroll") for (int q=0;q<4;q++){ \
      float sm=0.f, sq=0.f; \
      _Pragma("unroll") for (int ct=0;ct<8;ct++){ float v=ACCA[ct][q]; sm+=v; sq+=v*v; } \
      sm += __shfl_xor(sm,1); sq += __shfl_xor(sq,1); \
      sm += __shfl_xor(sm,2); sq += __shfl_xor(sq,2); \
      sm += __shfl_xor(sm,4); sq += __shfl_xor(sq,4); \
      sm += __shfl_xor(sm,8); sq += __shfl_xor(sq,8); \
      float m = sm*(1.0f/HH); \
      float inv = 1.0f/sqrtf(sq*(1.0f/HH) - m*m + 1e-5f); \
      int rowL = R0 + (RT)*16 + g*4 + q; \
      _Pragma("unroll") for (int ct=0;ct<8;ct++){ int col = ct*16 + c; \
        h[(g0+rowL)*HH + col] = (ACCA[ct][q]-m)*inv*og[col] + ob[col]; } }
  DLN(acc0, 0)
  DLN(acc1, 1)
}

// ================= mean pool partials =================
__global__ void k_pool(const float* __restrict__ hbuf, float* __restrict__ part)
{
  int hh = threadIdx.x; int seg = blockIdx.x, b = blockIdx.y;
  float sum=0.f;
  long base = ((long)b*LL + (long)seg*128)*HH + hh;
  for (int i=0;i<128;i++) sum += hbuf[base + (long)i*HH];
  part[((long)seg*BB + b)*HH + hh] = sum;
}

// ================= classifier head (fp32 out) =================
__global__ void k_cls(const float* __restrict__ part, const float* __restrict__ Wc1,
                      const float* __restrict__ bc1, const float* __restrict__ Wc2,
                      const float* __restrict__ bc2, float* __restrict__ out)
{
  __shared__ float pooled[BB*HH];
  __shared__ float zs[BB*64];
  int tid = threadIdx.x;
  for (int k=0;k<8;k++){
    int e = tid + k*256; int b = e>>7, hh = e&127;
    float s = 0.f;
    for (int seg=0; seg<64; seg++) s += part[((long)seg*BB + b)*HH + hh];
    pooled[e] = s * (1.0f/(float)LL);
  }
  __syncthreads();
  for (int k=0;k<4;k++){
    int e = tid + k*256; int b = e>>6, j = e&63;
    float s = bc1[j];
    for (int hh=0; hh<HH; hh++) s += pooled[b*HH+hh]*Wc1[hh*64+j];
    zs[e] = fmaxf(s, 0.0f);
  }
  __syncthreads();
  if (tid < BB*3){
    int b = tid/3, cc = tid%3;
    float s = bc2[cc];
    for (int j=0;j<64;j++) s += zs[b*64+j]*Wc2[j*3+cc];
    out[tid] = s;
  }
}

extern "C" void kernel_launch(void* const* d_in, const int* in_sizes, int n_in,
                              void* d_out, int out_size, void* d_ws, size_t ws_size,
                              hipStream_t stream) {
  const float* x       = (const float*)d_in[0];
  const float* W_in    = (const float*)d_in[1];
  const float* b_in    = (const float*)d_in[2];
  const float* attn_g  = (const float*)d_in[3];
  const float* attn_b  = (const float*)d_in[4];
  const float* Lam_re  = (const float*)d_in[5];
  const float* Lam_im  = (const float*)d_in[6];
  const float* B_re    = (const float*)d_in[7];
  const float* B_im    = (const float*)d_in[8];
  const float* C_re    = (const float*)d_in[9];
  const float* C_im    = (const float*)d_in[10];
  const float* Dv      = (const float*)d_in[11];
  const float* log_step= (const float*)d_in[12];
  const float* ff_g    = (const float*)d_in[13];
  const float* ff_b    = (const float*)d_in[14];
  const float* W_enc   = (const float*)d_in[15];
  const float* W_dec   = (const float*)d_in[16];
  const float* out_g   = (const float*)d_in[17];
  const float* out_b   = (const float*)d_in[18];
  const float* Wc1     = (const float*)d_in[19];
  const float* bc1     = (const float*)d_in[20];
  const float* Wc2     = (const float*)d_in[21];
  const float* bc2     = (const float*)d_in[22];
  float* ws = (float*)d_ws;

  float* hbuf = ws + OFF_H;
  u16* fxb = (u16*)(ws + OFF_FX);
  u16* xfb = (u16*)(ws + OFF_XF);   // xf, then fy
  u16* xbb = (u16*)(ws + OFF_XB);   // xb, then t
  u16* bub = (u16*)(ws + OFF_BU);

  k_pre<<<NLAY, 256, 0, stream>>>(Lam_re, Lam_im, B_re, B_im, C_re, C_im,
                                  W_enc, W_dec, log_step, ws);
  k_inproj<<<dim3(LL/256, BB), 256, 0, stream>>>(x, W_in, b_in, hbuf);

  for (int i=0;i<NLAY;i++){
    const u16* pk = (const u16*)(ws + OFF_PC + (unsigned long)i*PCS);
    const float* cons = ws + OFF_PC + (unsigned long)i*PCS + 49152;
    k_ln1<<<ROWS/4, 256, 0, stream>>>(hbuf, fxb, attn_g+i*HH, attn_b+i*HH);
    k_gemm_bu<<<ROWS/128, 256, 0, stream>>>(fxb, pk, bub);
    k_scanA<<<dim3(NCH,BB), 64, 0, stream>>>(bub, cons, ws);
    k_scanB<<<BB, 64, 0, stream>>>(cons, ws);
    k_scanC<<<dim3(NCH,BB), 64, 0, stream>>>(bub, xfb, xbb, cons, ws);
    k_gemm_y<<<ROWS/128, 256, 0, stream>>>(xfb, xbb, fxb, pk + 16384,
                                           Dv+i*HH, ff_g+i*HH, ff_b+i*HH);
    k_gemm_enc<<<ROWS/128, 256, 0, stream>>>(xfb, pk + 49152, xbb);
    k_gemm_dec<<<ROWS/128, 256, 0, stream>>>(xbb, xfb, hbuf, pk + 81920,
                                             out_g+i*HH, out_b+i*HH);
  }
  k_pool<<<dim3(64,BB), 128, 0, stream>>>(hbuf, ws + OFF_EF);
  k_cls<<<1, 256, 0, stream>>>(ws + OFF_EF, Wc1, bc1, Wc2, bc2, (float*)d_out);
}

// Round 6
// 690.681 us; speedup vs baseline: 22.0948x; 1.0248x over previous
//
#include <hip/hip_runtime.h>
#include <math.h>

#define NLAY 2
#define BB 16
#define LL 8192
#define HH 128
#define PP 64
#define CIN 64
#define CHS 64            // scan chunk size
#define NCH 128           // LL/CHS
#define ROWS (BB*LL)      // 131072

typedef unsigned short u16;
typedef __attribute__((ext_vector_type(8))) short  bf16x8;
typedef __attribute__((ext_vector_type(4))) float  f32x4;

// ---- workspace layout (float offsets) ----
#define OFF_H   0ul               // h fp32 [ROWS][128]
#define OFF_FX  16777216ul        // fx bf16 [ROWS][128]
#define OFF_XF  25165824ul        // xf bf16
#define OFF_XB  33554432ul        // xb bf16
#define OFF_BU  41943040ul        // bu bf16
#define OFF_EF  50331648ul        // 8 carry arrays x 131072 floats; pool partials reuse
#define OFF_PC  51380224ul
#define PCS     49408ul           // per-layer: packs 49152 floats (98304 bf16) + 256 consts
#define EFS     131072ul

__device__ __forceinline__ float gelu_(float x){
  return 0.5f*x*(1.0f + erff(x*0.70710678118654752440f));
}
__device__ __forceinline__ u16 f2bf(float f){
  unsigned int u = __float_as_uint(f);
  return (u16)((u + 0x7fffu + ((u>>16)&1u)) >> 16);
}
__device__ __forceinline__ float bf2f(u16 v){
  return __uint_as_float(((unsigned int)v)<<16);
}

// ================= precompute (parallelized: grid (NLAY,16)) =================
// pack layout (bf16 units): bu @0 (16384), y @16384 (32768), enc @49152 (32768), dec @81920 (16384)
// fragment: pack[((ct*KS + ks)*64 + lane)*8 + j] = Wt[col = ct*16 + (lane&15)][k = ks*32 + (lane>>4)*8 + j]
__global__ void k_pre(const float* __restrict__ Lam_re, const float* __restrict__ Lam_im,
                      const float* __restrict__ B_re, const float* __restrict__ B_im,
                      const float* __restrict__ C_re, const float* __restrict__ C_im,
                      const float* __restrict__ W_enc, const float* __restrict__ W_dec,
                      const float* __restrict__ log_step, float* __restrict__ ws)
{
  int i = blockIdx.x, sl = blockIdx.y, tid = threadIdx.x;
  float* pcf = ws + OFF_PC + (unsigned long)i*PCS;
  u16* pb = (u16*)pcf;
  float* cons = pcf + 49152;
  __shared__ float qre[PP], qim[PP];
  if (tid < PP){
    int p = tid;
    float lre = Lam_re[i*PP+p], lim = Lam_im[i*PP+p];
    float st = expf(log_step[i*PP+p]);
    float er = expf(lre*st), ang = lim*st;
    float Lr = er*cosf(ang), Li = er*sinf(ang);
    float wr = Lr - 1.0f, wi = Li;
    float den = lre*lre + lim*lim;
    qre[p] = (wr*lre + wi*lim)/den;
    qim[p] = (wi*lre - wr*lim)/den;
    if (sl == 0){
      cons[p] = Lr; cons[64+p] = Li;
      float ec = expf(lre*st*(float)CHS), ac = lim*st*(float)CHS;
      cons[128+p] = ec*cosf(ac); cons[192+p] = ec*sinf(ac);
    }
  }
  __syncthreads();
  // bu pack: Wt[col][k]: col=cc*64+p over [re|im], k=h
  for (int t0 = sl*1024 + tid; t0 < (sl+1)*1024; t0 += 256){
    int j = t0&7, ln = (t0>>3)&63, ks = (t0>>9)&3, ct = t0>>11;
    int col = ct*16 + (ln&15);
    int k = ks*32 + (ln>>4)*8 + j;
    int cc = col>>6, p = col&63;
    float br = B_re[(i*PP+p)*HH + k], bi = B_im[(i*PP+p)*HH + k];
    pb[t0] = f2bf(cc ? (qre[p]*bi + qim[p]*br) : (qre[p]*br - qim[p]*bi));
  }
  // y pack
  for (int t0 = sl*2048 + tid; t0 < (sl+1)*2048; t0 += 256){
    int j = t0&7, ln = (t0>>3)&63, ks = (t0>>9)&7, ct = t0>>12;
    int hh = ct*16 + (ln&15);
    int k = ks*32 + (ln>>4)*8 + j;
    int blk = k>>6, p = k&63;
    int base = (i*HH + hh)*(2*PP);
    float v = (blk==0)? C_re[base+p] : (blk==1)? -C_im[base+p]
            : (blk==2)? C_re[base+PP+p] : -C_im[base+PP+p];
    pb[16384 + t0] = f2bf(v);
  }
  // enc pack
  for (int t0 = sl*2048 + tid; t0 < (sl+1)*2048; t0 += 256){
    int j = t0&7, ln = (t0>>3)&63, ks = (t0>>9)&3, ct = t0>>11;
    int colj = (ct<8) ? ct*16 + (ln&15) : 128 + (ct-8)*16 + (ln&15);
    int k = ks*32 + (ln>>4)*8 + j;
    pb[49152 + t0] = f2bf(W_enc[((long)i*HH + k)*(2*HH) + colj]);
  }
  // dec pack
  for (int t0 = sl*1024 + tid; t0 < (sl+1)*1024; t0 += 256){
    int j = t0&7, ln = (t0>>3)&63, ks = (t0>>9)&3, ct = t0>>11;
    int col = ct*16 + (ln&15);
    int k = ks*32 + (ln>>4)*8 + j;
    pb[81920 + t0] = f2bf(W_dec[((long)i*HH + k)*HH + col]);
  }
}

// ================= input projection (fp32 VALU) =================
#define WRITEOUT32(ARR, COLBASE, DST) \
  __syncthreads(); \
  _Pragma("unroll") \
  for (int jj=0;jj<32;jj++) s[tid*33+jj] = ARR[jj]; \
  __syncthreads(); \
  _Pragma("unroll") \
  for (int k2=0;k2<32;k2++){ int e = tid + k2*256; int r = e>>5, jj = e&31; \
    (DST)[(g0+(long)r)*HH + (COLBASE) + jj] = s[r*33+jj]; }

__global__ __launch_bounds__(256,2) void k_inproj(const float* __restrict__ x,
                         const float* __restrict__ W_in,
                         const float* __restrict__ b_in, float* __restrict__ hout)
{
  __shared__ float s[256*33];
  int tid = threadIdx.x;
  int b = blockIdx.y;
  int l0 = blockIdx.x*256;
  long g0 = (long)b*LL + l0;
  float c0[32], c1[32], c2[32], c3[32];
  #pragma unroll
  for (int j=0;j<32;j++){ c0[j]=b_in[j]; c1[j]=b_in[32+j]; c2[j]=b_in[64+j]; c3[j]=b_in[96+j]; }
  #define INP_CHUNK(KC) { \
    __syncthreads(); \
    _Pragma("unroll") \
    for (int k2=0;k2<32;k2++){ \
      s[tid*33+k2] = x[((long)b*CIN + (KC)*32+k2)*LL + l0 + tid]; } \
    __syncthreads(); \
    _Pragma("unroll 2") \
    for (int kk=0;kk<32;kk++){ \
      float a = s[tid*33+kk]; \
      const float* wr = W_in + ((KC)*32+kk)*HH; \
      _Pragma("unroll") \
      for (int j=0;j<32;j++){ c0[j]+=a*wr[j]; c1[j]+=a*wr[32+j]; c2[j]+=a*wr[64+j]; c3[j]+=a*wr[96+j]; } \
    } }
  INP_CHUNK(0) INP_CHUNK(1)
  WRITEOUT32(c0, 0, hout)
  WRITEOUT32(c1, 32, hout)
  WRITEOUT32(c2, 64, hout)
  WRITEOUT32(c3, 96, hout)
}

// ================= LN1: h fp32 -> fx bf16 =================
__global__ void k_ln1(const float* __restrict__ src, u16* __restrict__ dst,
                      const float* __restrict__ g, const float* __restrict__ bta)
{
  int wv = threadIdx.x>>6, lane = threadIdx.x&63;
  long row = (long)blockIdx.x*4 + wv;
  long o = row*HH;
  float a0 = src[o+lane], a1 = src[o+lane+64];
  float sum = a0+a1, sq = a0*a0+a1*a1;
  #pragma unroll
  for (int of=1;of<64;of<<=1){ sum += __shfl_xor(sum,of); sq += __shfl_xor(sq,of); }
  float m = sum*(1.0f/HH);
  float inv = 1.0f/sqrtf(sq*(1.0f/HH) - m*m + 1e-5f);
  dst[o+lane]    = f2bf((a0-m)*inv*g[lane]    + bta[lane]);
  dst[o+lane+64] = f2bf((a1-m)*inv*g[lane+64] + bta[lane+64]);
}

// ================= GEMM skeleton macros =================
#define GEMM_PRE \
  __shared__ u16 sA[128*136]; \
  int tid = threadIdx.x; long g0 = (long)blockIdx.x*128; \
  int lane = tid & 63, wid = tid >> 6; \
  int g = lane >> 4, c = lane & 15; \
  int R0 = wid*32; (void)g; (void)c; (void)R0;

#define STAGE_BF(SRC) do{ __syncthreads(); \
  _Pragma("unroll") \
  for (int rep=0; rep<8; rep++){ int e = tid + rep*256; \
    int r = e>>4, c8 = (e&15)*8; \
    *(bf16x8*)&sA[r*136 + c8] = *(const bf16x8*)((SRC) + (g0 + r)*HH + c8); } \
  __syncthreads(); }while(0)

#define MAINLOOP8(PACK, ACCA, ACCB, KSTOT, KSOFF) do{ \
  _Pragma("unroll") \
  for (int ks=0; ks<4; ks++){ \
    bf16x8 a0 = *(const bf16x8*)&sA[(R0 + c)*136 + ks*32 + g*8]; \
    bf16x8 a1 = *(const bf16x8*)&sA[(R0 + 16 + c)*136 + ks*32 + g*8]; \
    _Pragma("unroll") \
    for (int ct=0; ct<8; ct++){ \
      bf16x8 b = ((const bf16x8*)(PACK))[(ct*(KSTOT) + (KSOFF) + ks)*64 + lane]; \
      ACCA[ct] = __builtin_amdgcn_mfma_f32_16x16x32_bf16(a0, b, ACCA[ct], 0,0,0); \
      ACCB[ct] = __builtin_amdgcn_mfma_f32_16x16x32_bf16(a1, b, ACCB[ct], 0,0,0); } } }while(0)

#define ACC_ZERO(ACCA, ACCB) \
  f32x4 ACCA[8], ACCB[8]; \
  { f32x4 z = {0.f,0.f,0.f,0.f}; \
    _Pragma("unroll") for (int ct=0; ct<8; ct++){ ACCA[ct]=z; ACCB[ct]=z; } }

// ================= bu = fx @ W_bu (bf16 out) =================
__global__ __launch_bounds__(256,2) void k_gemm_bu(const u16* __restrict__ fxb,
                      const u16* __restrict__ pack, u16* __restrict__ bub)
{
  GEMM_PRE
  ACC_ZERO(acc0, acc1)
  STAGE_BF(fxb);
  MAINLOOP8(pack, acc0, acc1, 4, 0);
  #define BUST(ACCA, RT) \
    _Pragma("unroll") for (int ct=0; ct<8; ct++){ int col = ct*16 + c; \
      _Pragma("unroll") for (int q=0;q<4;q++){ \
        int rowL = R0 + (RT)*16 + g*4 + q; \
        bub[(g0+rowL)*HH + col] = f2bf(ACCA[ct][q]); } }
  BUST(acc0, 0)
  BUST(acc1, 1)
}

// ================= scan A: per-chunk fwd/bwd reductions =================
__global__ void k_scanA(const u16* __restrict__ bub, const float* __restrict__ cons,
                        float* __restrict__ ws)
{
  int p = threadIdx.x; int ch = blockIdx.x, b = blockIdx.y;
  float Lr = cons[p], Li = cons[64+p];
  float efr=0.f, efi=0.f, ebr=0.f, ebi=0.f, pwr=1.f, pwi=0.f;
  long base = ((long)b*LL + (long)ch*CHS)*HH;
  for (int i=0;i<CHS;i++){
    float br = bf2f(bub[base + (long)i*HH + p]);
    float bi = bf2f(bub[base + (long)i*HH + 64 + p]);
    float nr = Lr*efr - Li*efi + br;
    efi = Lr*efi + Li*efr + bi; efr = nr;
    ebr += pwr*br - pwi*bi;
    ebi += pwr*bi + pwi*br;
    float tr = pwr*Lr - pwi*Li;
    pwi = pwr*Li + pwi*Lr; pwr = tr;
  }
  long o = ((long)b*NCH + ch)*PP + p;
  ws[OFF_EF + o]       = efr;  ws[OFF_EF+EFS + o]   = efi;
  ws[OFF_EF+2*EFS + o] = ebr;  ws[OFF_EF+3*EFS + o] = ebi;
}

// ================= scan B: carry scan over chunks =================
__global__ void k_scanB(const float* __restrict__ cons, float* __restrict__ ws)
{
  int p = threadIdx.x; int b = blockIdx.x;
  float Cr = cons[128+p], Ci = cons[192+p];
  float Fr=0.f, Fi=0.f;
  for (int ch=0;ch<NCH;ch++){
    long o = ((long)b*NCH + ch)*PP + p;
    ws[OFF_EF+4*EFS + o] = Fr;
    ws[OFF_EF+5*EFS + o] = Fi;
    float er = ws[OFF_EF + o], ei = ws[OFF_EF+EFS + o];
    float nr = Cr*Fr - Ci*Fi + er;
    Fi = Cr*Fi + Ci*Fr + ei; Fr = nr;
  }
  float Xr=0.f, Xi=0.f;
  for (int ch=NCH-1;ch>=0;ch--){
    long o = ((long)b*NCH + ch)*PP + p;
    ws[OFF_EF+6*EFS + o] = Xr;
    ws[OFF_EF+7*EFS + o] = Xi;
    float er = ws[OFF_EF+2*EFS + o], ei = ws[OFF_EF+3*EFS + o];
    float nr = er + Cr*Xr - Ci*Xi;
    Xi = ei + Cr*Xi + Ci*Xr; Xr = nr;
  }
}

// ================= scan C: final inclusive scans; bf16 xf/xb out =================
__global__ void k_scanC(const u16* __restrict__ bub, u16* __restrict__ xfb,
                        u16* __restrict__ xbb, const float* __restrict__ cons,
                        const float* __restrict__ wsc)
{
  int p = threadIdx.x; int ch = blockIdx.x, b = blockIdx.y;
  float Lr = cons[p], Li = cons[64+p];
  long o = ((long)b*NCH + ch)*PP + p;
  float xr = wsc[OFF_EF+4*EFS + o], xi = wsc[OFF_EF+5*EFS + o];
  long base = ((long)b*LL + (long)ch*CHS)*HH;
  for (int i=0;i<CHS;i++){
    long a0 = base + (long)i*HH;
    float br = bf2f(bub[a0+p]), bi = bf2f(bub[a0+64+p]);
    float nr = Lr*xr - Li*xi + br;
    xi = Lr*xi + Li*xr + bi; xr = nr;
    xfb[a0+p] = f2bf(xr); xfb[a0+64+p] = f2bf(xi);
  }
  float yr = wsc[OFF_EF+6*EFS + o], yi = wsc[OFF_EF+7*EFS + o];
  for (int i=CHS-1;i>=0;i--){
    long a0 = base + (long)i*HH;
    float br = bf2f(bub[a0+p]), bi = bf2f(bub[a0+64+p]);
    float nr = Lr*yr - Li*yi + br;
    yi = Lr*yi + Li*yr + bi; yr = nr;
    xbb[a0+p] = f2bf(yr); xbb[a0+64+p] = f2bf(yi);
  }
}

// ================= fused post: y=xs@Wy; a=gelu(y+D*fx)+fx; fy=LN2(a);
//                   [v|gt]=fy@Wenc; t=v*gelu(gt); blk=t@Wdec;
//                   h=LN3(blk+fy+h) =================
__global__ __launch_bounds__(256,2) void k_post(const u16* __restrict__ xfb,
                      const u16* __restrict__ xbb, const u16* __restrict__ fxb,
                      const u16* __restrict__ packy, const u16* __restrict__ packe,
                      const u16* __restrict__ packd, float* __restrict__ h,
                      const float* __restrict__ Dv,
                      const float* __restrict__ fg, const float* __restrict__ fb,
                      const float* __restrict__ og, const float* __restrict__ ob)
{
  GEMM_PRE
  // ---- y GEMM (K=256 over xf|xb) ----
  ACC_ZERO(fy0, fy1)
  STAGE_BF(xfb);
  MAINLOOP8(packy, fy0, fy1, 8, 0);
  STAGE_BF(xbb);
  MAINLOOP8(packy, fy0, fy1, 8, 4);
  // ---- a = gelu(y + D*fx) + fx ----
  #define YEPI(ACCA, RT) \
    _Pragma("unroll") for (int ct=0; ct<8; ct++){ int col = ct*16 + c; \
      float dvc = Dv[col]; \
      _Pragma("unroll") for (int q=0;q<4;q++){ \
        int rowL = R0 + (RT)*16 + g*4 + q; \
        float fxv = bf2f(fxb[(g0+rowL)*HH + col]); \
        ACCA[ct][q] = gelu_(ACCA[ct][q] + dvc*fxv) + fxv; } }
  YEPI(fy0, 0)
  YEPI(fy1, 1)
  // ---- LN2 -> fy (regs), also scatter bf16 fy into sA for enc A-fragments ----
  __syncthreads();   // all waves done reading xb tile
  #define YLN(ACCA, RT) \
    _Pragma("unroll") for (int q=0;q<4;q++){ \
      float sm=0.f, sq=0.f; \
      _Pragma("unroll") for (int ct=0;ct<8;ct++){ float v=ACCA[ct][q]; sm+=v; sq+=v*v; } \
      sm += __shfl_xor(sm,1); sq += __shfl_xor(sq,1); \
      sm += __shfl_xor(sm,2); sq += __shfl_xor(sq,2); \
      sm += __shfl_xor(sm,4); sq += __shfl_xor(sq,4); \
      sm += __shfl_xor(sm,8); sq += __shfl_xor(sq,8); \
      float m = sm*(1.0f/HH); \
      float inv = 1.0f/sqrtf(sq*(1.0f/HH) - m*m + 1e-5f); \
      int rowL = R0 + (RT)*16 + g*4 + q; \
      _Pragma("unroll") for (int ct=0;ct<8;ct++){ int col = ct*16 + c; \
        float v = (ACCA[ct][q]-m)*inv*fg[col] + fb[col]; \
        ACCA[ct][q] = v; \
        sA[rowL*136 + col] = f2bf(v); } }
  YLN(fy0, 0)
  YLN(fy1, 1)
  __syncthreads();
  // ---- enc GEMM: [v|gt] = fy @ Wenc ----
  f32x4 av0[8], av1[8], ag0[8], ag1[8];
  { f32x4 z = {0.f,0.f,0.f,0.f};
    #pragma unroll
    for (int ct=0; ct<8; ct++){ av0[ct]=z; av1[ct]=z; ag0[ct]=z; ag1[ct]=z; } }
  #pragma unroll
  for (int ks=0; ks<4; ks++){
    bf16x8 a0 = *(const bf16x8*)&sA[(R0 + c)*136 + ks*32 + g*8];
    bf16x8 a1 = *(const bf16x8*)&sA[(R0 + 16 + c)*136 + ks*32 + g*8];
    #pragma unroll
    for (int ct=0; ct<8; ct++){
      bf16x8 bv = ((const bf16x8*)packe)[(ct*4 + ks)*64 + lane];
      av0[ct] = __builtin_amdgcn_mfma_f32_16x16x32_bf16(a0, bv, av0[ct], 0,0,0);
      av1[ct] = __builtin_amdgcn_mfma_f32_16x16x32_bf16(a1, bv, av1[ct], 0,0,0);
      bf16x8 bg = ((const bf16x8*)packe)[((ct+8)*4 + ks)*64 + lane];
      ag0[ct] = __builtin_amdgcn_mfma_f32_16x16x32_bf16(a0, bg, ag0[ct], 0,0,0);
      ag1[ct] = __builtin_amdgcn_mfma_f32_16x16x32_bf16(a1, bg, ag1[ct], 0,0,0);
    }
  }
  // ---- t = v * gelu(gt) -> sA ----
  __syncthreads();
  #define T2LDS(VA, GA, RT) \
    _Pragma("unroll") for (int ct=0; ct<8; ct++){ int col = ct*16 + c; \
      _Pragma("unroll") for (int q=0;q<4;q++){ \
        int rowL = R0 + (RT)*16 + g*4 + q; \
        sA[rowL*136 + col] = f2bf(VA[ct][q] * gelu_(GA[ct][q])); } }
  T2LDS(av0, ag0, 0)
  T2LDS(av1, ag1, 1)
  __syncthreads();
  // ---- dec GEMM: blk = t @ Wdec ----
  ACC_ZERO(ad0, ad1)
  MAINLOOP8(packd, ad0, ad1, 4, 0);
  // ---- blk + fy + h residual, LN3, write h ----
  #define DADD(AD, AF, RT) \
    _Pragma("unroll") for (int ct=0; ct<8; ct++){ int col = ct*16 + c; \
      _Pragma("unroll") for (int q=0;q<4;q++){ \
        int rowL = R0 + (RT)*16 + g*4 + q; long ix = (g0+rowL)*HH + col; \
        AD[ct][q] += AF[ct][q] + h[ix]; } }
  DADD(ad0, fy0, 0)
  DADD(ad1, fy1, 1)
  #define DLN(ACCA, RT) \
    _Pragma("unroll") for (int q=0;q<4;q++){ \
      float sm=0.f, sq=0.f; \
      _Pragma("unroll") for (int ct=0;ct<8;ct++){ float v=ACCA[ct][q]; sm+=v; sq+=v*v; } \
      sm += __shfl_xor(sm,1); sq += __shfl_xor(sq,1); \
      sm += __shfl_xor(sm,2); sq += __shfl_xor(sq,2); \
      sm += __shfl_xor(sm,4); sq += __shfl_xor(sq,4); \
      sm += __shfl_xor(sm,8); sq += __shfl_xor(sq,8); \
      float m = sm*(1.0f/HH); \
      float inv = 1.0f/sqrtf(sq*(1.0f/HH) - m*m + 1e-5f); \
      int rowL = R0 + (RT)*16 + g*4 + q; \
      _Pragma("unroll") for (int ct=0;ct<8;ct++){ int col = ct*16 + c; \
        h[(g0+rowL)*HH + col] = (ACCA[ct][q]-m)*inv*og[col] + ob[col]; } }
  DLN(ad0, 0)
  DLN(ad1, 1)
}

// ================= mean pool partials =================
__global__ void k_pool(const float* __restrict__ hbuf, float* __restrict__ part)
{
  int hh = threadIdx.x; int seg = blockIdx.x, b = blockIdx.y;
  float sum=0.f;
  long base = ((long)b*LL + (long)seg*128)*HH + hh;
  for (int i=0;i<128;i++) sum += hbuf[base + (long)i*HH];
  part[((long)seg*BB + b)*HH + hh] = sum;
}

// ================= classifier head (fp32 out) =================
__global__ void k_cls(const float* __restrict__ part, const float* __restrict__ Wc1,
                      const float* __restrict__ bc1, const float* __restrict__ Wc2,
                      const float* __restrict__ bc2, float* __restrict__ out)
{
  __shared__ float pooled[BB*HH];
  __shared__ float zs[BB*64];
  int tid = threadIdx.x;
  for (int k=0;k<8;k++){
    int e = tid + k*256; int b = e>>7, hh = e&127;
    float s = 0.f;
    for (int seg=0; seg<64; seg++) s += part[((long)seg*BB + b)*HH + hh];
    pooled[e] = s * (1.0f/(float)LL);
  }
  __syncthreads();
  for (int k=0;k<4;k++){
    int e = tid + k*256; int b = e>>6, j = e&63;
    float s = bc1[j];
    for (int hh=0; hh<HH; hh++) s += pooled[b*HH+hh]*Wc1[hh*64+j];
    zs[e] = fmaxf(s, 0.0f);
  }
  __syncthreads();
  if (tid < BB*3){
    int b = tid/3, cc = tid%3;
    float s = bc2[cc];
    for (int j=0;j<64;j++) s += zs[b*64+j]*Wc2[j*3+cc];
    out[tid] = s;
  }
}

extern "C" void kernel_launch(void* const* d_in, const int* in_sizes, int n_in,
                              void* d_out, int out_size, void* d_ws, size_t ws_size,
                              hipStream_t stream) {
  const float* x       = (const float*)d_in[0];
  const float* W_in    = (const float*)d_in[1];
  const float* b_in    = (const float*)d_in[2];
  const float* attn_g  = (const float*)d_in[3];
  const float* attn_b  = (const float*)d_in[4];
  const float* Lam_re  = (const float*)d_in[5];
  const float* Lam_im  = (const float*)d_in[6];
  const float* B_re    = (const float*)d_in[7];
  const float* B_im    = (const float*)d_in[8];
  const float* C_re    = (const float*)d_in[9];
  const float* C_im    = (const float*)d_in[10];
  const float* Dv      = (const float*)d_in[11];
  const float* log_step= (const float*)d_in[12];
  const float* ff_g    = (const float*)d_in[13];
  const float* ff_b    = (const float*)d_in[14];
  const float* W_enc   = (const float*)d_in[15];
  const float* W_dec   = (const float*)d_in[16];
  const float* out_g   = (const float*)d_in[17];
  const float* out_b   = (const float*)d_in[18];
  const float* Wc1     = (const float*)d_in[19];
  const float* bc1     = (const float*)d_in[20];
  const float* Wc2     = (const float*)d_in[21];
  const float* bc2     = (const float*)d_in[22];
  float* ws = (float*)d_ws;

  float* hbuf = ws + OFF_H;
  u16* fxb = (u16*)(ws + OFF_FX);
  u16* xfb = (u16*)(ws + OFF_XF);
  u16* xbb = (u16*)(ws + OFF_XB);
  u16* bub = (u16*)(ws + OFF_BU);

  k_pre<<<dim3(NLAY,16), 256, 0, stream>>>(Lam_re, Lam_im, B_re, B_im, C_re, C_im,
                                           W_enc, W_dec, log_step, ws);
  k_inproj<<<dim3(LL/256, BB), 256, 0, stream>>>(x, W_in, b_in, hbuf);

  for (int i=0;i<NLAY;i++){
    const u16* pk = (const u16*)(ws + OFF_PC + (unsigned long)i*PCS);
    const float* cons = ws + OFF_PC + (unsigned long)i*PCS + 49152;
    k_ln1<<<ROWS/4, 256, 0, stream>>>(hbuf, fxb, attn_g+i*HH, attn_b+i*HH);
    k_gemm_bu<<<ROWS/128, 256, 0, stream>>>(fxb, pk, bub);
    k_scanA<<<dim3(NCH,BB), 64, 0, stream>>>(bub, cons, ws);
    k_scanB<<<BB, 64, 0, stream>>>(cons, ws);
    k_scanC<<<dim3(NCH,BB), 64, 0, stream>>>(bub, xfb, xbb, cons, ws);
    k_post<<<ROWS/128, 256, 0, stream>>>(xfb, xbb, fxb, pk + 16384, pk + 49152,
                                         pk + 81920, hbuf, Dv+i*HH,
                                         ff_g+i*HH, ff_b+i*HH, out_g+i*HH, out_b+i*HH);
  }
  k_pool<<<dim3(64,BB), 128, 0, stream>>>(hbuf, ws + OFF_EF);
  k_cls<<<1, 256, 0, stream>>>(ws + OFF_EF, Wc1, bc1, Wc2, bc2, (float*)d_out);
}

// Round 7
// 555.809 us; speedup vs baseline: 27.4563x; 1.2427x over previous
//
#include <hip/hip_runtime.h>
#include <math.h>

#define NLAY 2
#define BB 16
#define LL 8192
#define HH 128
#define PP 64
#define CIN 64
#define CHS 64            // scan chunk size
#define NCH 128           // LL/CHS
#define ROWS (BB*LL)      // 131072

typedef unsigned short u16;
typedef __attribute__((ext_vector_type(8))) short  bf16x8;
typedef __attribute__((ext_vector_type(4))) float  f32x4;

// ---- workspace layout (float offsets) ----
#define OFF_H   0ul               // h fp32 [ROWS][128]
#define OFF_FX  16777216ul        // fx bf16 [ROWS][128]
#define OFF_XF  25165824ul        // xf bf16
#define OFF_XB  33554432ul        // xb bf16
#define OFF_BU  41943040ul        // bu bf16
#define OFF_EF  50331648ul        // 8 carry arrays x 131072 floats; pool partials reuse
#define OFF_PC  51380224ul
#define PCS     49408ul           // per-layer: packs 49152 floats (98304 bf16) + 256 consts
#define EFS     131072ul

__device__ __forceinline__ float gelu_(float x){
  return 0.5f*x*(1.0f + erff(x*0.70710678118654752440f));
}
__device__ __forceinline__ u16 f2bf(float f){
  unsigned int u = __float_as_uint(f);
  return (u16)((u + 0x7fffu + ((u>>16)&1u)) >> 16);
}
__device__ __forceinline__ float bf2f(u16 v){
  return __uint_as_float(((unsigned int)v)<<16);
}

// ================= precompute (parallelized: grid (NLAY,16)) =================
// pack layout (bf16 units): bu @0 (16384), y @16384 (32768), enc @49152 (32768), dec @81920 (16384)
// fragment: pack[((ct*KS + ks)*64 + lane)*8 + j] = Wt[col = ct*16 + (lane&15)][k = ks*32 + (lane>>4)*8 + j]
__global__ void k_pre(const float* __restrict__ Lam_re, const float* __restrict__ Lam_im,
                      const float* __restrict__ B_re, const float* __restrict__ B_im,
                      const float* __restrict__ C_re, const float* __restrict__ C_im,
                      const float* __restrict__ W_enc, const float* __restrict__ W_dec,
                      const float* __restrict__ log_step, float* __restrict__ ws)
{
  int i = blockIdx.x, sl = blockIdx.y, tid = threadIdx.x;
  float* pcf = ws + OFF_PC + (unsigned long)i*PCS;
  u16* pb = (u16*)pcf;
  float* cons = pcf + 49152;
  __shared__ float qre[PP], qim[PP];
  if (tid < PP){
    int p = tid;
    float lre = Lam_re[i*PP+p], lim = Lam_im[i*PP+p];
    float st = expf(log_step[i*PP+p]);
    float er = expf(lre*st), ang = lim*st;
    float Lr = er*cosf(ang), Li = er*sinf(ang);
    float wr = Lr - 1.0f, wi = Li;
    float den = lre*lre + lim*lim;
    qre[p] = (wr*lre + wi*lim)/den;
    qim[p] = (wi*lre - wr*lim)/den;
    if (sl == 0){
      cons[p] = Lr; cons[64+p] = Li;
      float ec = expf(lre*st*(float)CHS), ac = lim*st*(float)CHS;
      cons[128+p] = ec*cosf(ac); cons[192+p] = ec*sinf(ac);
    }
  }
  __syncthreads();
  // bu pack
  for (int t0 = sl*1024 + tid; t0 < (sl+1)*1024; t0 += 256){
    int j = t0&7, ln = (t0>>3)&63, ks = (t0>>9)&3, ct = t0>>11;
    int col = ct*16 + (ln&15);
    int k = ks*32 + (ln>>4)*8 + j;
    int cc = col>>6, p = col&63;
    float br = B_re[(i*PP+p)*HH + k], bi = B_im[(i*PP+p)*HH + k];
    pb[t0] = f2bf(cc ? (qre[p]*bi + qim[p]*br) : (qre[p]*br - qim[p]*bi));
  }
  // y pack
  for (int t0 = sl*2048 + tid; t0 < (sl+1)*2048; t0 += 256){
    int j = t0&7, ln = (t0>>3)&63, ks = (t0>>9)&7, ct = t0>>12;
    int hh = ct*16 + (ln&15);
    int k = ks*32 + (ln>>4)*8 + j;
    int blk = k>>6, p = k&63;
    int base = (i*HH + hh)*(2*PP);
    float v = (blk==0)? C_re[base+p] : (blk==1)? -C_im[base+p]
            : (blk==2)? C_re[base+PP+p] : -C_im[base+PP+p];
    pb[16384 + t0] = f2bf(v);
  }
  // enc pack
  for (int t0 = sl*2048 + tid; t0 < (sl+1)*2048; t0 += 256){
    int j = t0&7, ln = (t0>>3)&63, ks = (t0>>9)&3, ct = t0>>11;
    int colj = (ct<8) ? ct*16 + (ln&15) : 128 + (ct-8)*16 + (ln&15);
    int k = ks*32 + (ln>>4)*8 + j;
    pb[49152 + t0] = f2bf(W_enc[((long)i*HH + k)*(2*HH) + colj]);
  }
  // dec pack
  for (int t0 = sl*1024 + tid; t0 < (sl+1)*1024; t0 += 256){
    int j = t0&7, ln = (t0>>3)&63, ks = (t0>>9)&3, ct = t0>>11;
    int col = ct*16 + (ln&15);
    int k = ks*32 + (ln>>4)*8 + j;
    pb[81920 + t0] = f2bf(W_dec[((long)i*HH + k)*HH + col]);
  }
}

// ================= input projection (fp32 VALU) =================
#define WRITEOUT32(ARR, COLBASE, DST) \
  __syncthreads(); \
  _Pragma("unroll") \
  for (int jj=0;jj<32;jj++) s[tid*33+jj] = ARR[jj]; \
  __syncthreads(); \
  _Pragma("unroll") \
  for (int k2=0;k2<32;k2++){ int e = tid + k2*256; int r = e>>5, jj = e&31; \
    (DST)[(g0+(long)r)*HH + (COLBASE) + jj] = s[r*33+jj]; }

__global__ __launch_bounds__(256,2) void k_inproj(const float* __restrict__ x,
                         const float* __restrict__ W_in,
                         const float* __restrict__ b_in, float* __restrict__ hout)
{
  __shared__ float s[256*33];
  int tid = threadIdx.x;
  int b = blockIdx.y;
  int l0 = blockIdx.x*256;
  long g0 = (long)b*LL + l0;
  float c0[32], c1[32], c2[32], c3[32];
  #pragma unroll
  for (int j=0;j<32;j++){ c0[j]=b_in[j]; c1[j]=b_in[32+j]; c2[j]=b_in[64+j]; c3[j]=b_in[96+j]; }
  #define INP_CHUNK(KC) { \
    __syncthreads(); \
    _Pragma("unroll") \
    for (int k2=0;k2<32;k2++){ \
      s[tid*33+k2] = x[((long)b*CIN + (KC)*32+k2)*LL + l0 + tid]; } \
    __syncthreads(); \
    _Pragma("unroll 2") \
    for (int kk=0;kk<32;kk++){ \
      float a = s[tid*33+kk]; \
      const float* wr = W_in + ((KC)*32+kk)*HH; \
      _Pragma("unroll") \
      for (int j=0;j<32;j++){ c0[j]+=a*wr[j]; c1[j]+=a*wr[32+j]; c2[j]+=a*wr[64+j]; c3[j]+=a*wr[96+j]; } \
    } }
  INP_CHUNK(0) INP_CHUNK(1)
  WRITEOUT32(c0, 0, hout)
  WRITEOUT32(c1, 32, hout)
  WRITEOUT32(c2, 64, hout)
  WRITEOUT32(c3, 96, hout)
}

// ================= LN1: h fp32 -> fx bf16 =================
__global__ void k_ln1(const float* __restrict__ src, u16* __restrict__ dst,
                      const float* __restrict__ g, const float* __restrict__ bta)
{
  int wv = threadIdx.x>>6, lane = threadIdx.x&63;
  long row = (long)blockIdx.x*4 + wv;
  long o = row*HH;
  float a0 = src[o+lane], a1 = src[o+lane+64];
  float sum = a0+a1, sq = a0*a0+a1*a1;
  #pragma unroll
  for (int of=1;of<64;of<<=1){ sum += __shfl_xor(sum,of); sq += __shfl_xor(sq,of); }
  float m = sum*(1.0f/HH);
  float inv = 1.0f/sqrtf(sq*(1.0f/HH) - m*m + 1e-5f);
  dst[o+lane]    = f2bf((a0-m)*inv*g[lane]    + bta[lane]);
  dst[o+lane+64] = f2bf((a1-m)*inv*g[lane+64] + bta[lane+64]);
}

// ================= GEMM skeleton macros =================
#define GEMM_PRE \
  __shared__ u16 sA[128*136]; \
  int tid = threadIdx.x; long g0 = (long)blockIdx.x*128; \
  int lane = tid & 63, wid = tid >> 6; \
  int g = lane >> 4, c = lane & 15; \
  int R0 = wid*32; (void)g; (void)c; (void)R0;

#define STAGE_BF(SRC) do{ __syncthreads(); \
  _Pragma("unroll") \
  for (int rep=0; rep<8; rep++){ int e = tid + rep*256; \
    int r = e>>4, c8 = (e&15)*8; \
    *(bf16x8*)&sA[r*136 + c8] = *(const bf16x8*)((SRC) + (g0 + r)*HH + c8); } \
  __syncthreads(); }while(0)

#define MAINLOOP8(PACK, ACCA, ACCB, KSTOT, KSOFF) do{ \
  _Pragma("unroll") \
  for (int ks=0; ks<4; ks++){ \
    bf16x8 a0 = *(const bf16x8*)&sA[(R0 + c)*136 + ks*32 + g*8]; \
    bf16x8 a1 = *(const bf16x8*)&sA[(R0 + 16 + c)*136 + ks*32 + g*8]; \
    _Pragma("unroll") \
    for (int ct=0; ct<8; ct++){ \
      bf16x8 b = ((const bf16x8*)(PACK))[(ct*(KSTOT) + (KSOFF) + ks)*64 + lane]; \
      ACCA[ct] = __builtin_amdgcn_mfma_f32_16x16x32_bf16(a0, b, ACCA[ct], 0,0,0); \
      ACCB[ct] = __builtin_amdgcn_mfma_f32_16x16x32_bf16(a1, b, ACCB[ct], 0,0,0); } } }while(0)

#define ACC_ZERO(ACCA, ACCB) \
  f32x4 ACCA[8], ACCB[8]; \
  { f32x4 z = {0.f,0.f,0.f,0.f}; \
    _Pragma("unroll") for (int ct=0; ct<8; ct++){ ACCA[ct]=z; ACCB[ct]=z; } }

// ================= bu = fx @ W_bu (bf16 out) =================
__global__ __launch_bounds__(256,2) void k_gemm_bu(const u16* __restrict__ fxb,
                      const u16* __restrict__ pack, u16* __restrict__ bub)
{
  GEMM_PRE
  ACC_ZERO(acc0, acc1)
  STAGE_BF(fxb);
  MAINLOOP8(pack, acc0, acc1, 4, 0);
  #define BUST(ACCA, RT) \
    _Pragma("unroll") for (int ct=0; ct<8; ct++){ int col = ct*16 + c; \
      _Pragma("unroll") for (int q=0;q<4;q++){ \
        int rowL = R0 + (RT)*16 + g*4 + q; \
        bub[(g0+rowL)*HH + col] = f2bf(ACCA[ct][q]); } }
  BUST(acc0, 0)
  BUST(acc1, 1)
}

// ================= scan A: per-chunk fwd/bwd reductions =================
__global__ void k_scanA(const u16* __restrict__ bub, const float* __restrict__ cons,
                        float* __restrict__ ws)
{
  int p = threadIdx.x; int ch = blockIdx.x, b = blockIdx.y;
  float Lr = cons[p], Li = cons[64+p];
  float efr=0.f, efi=0.f, ebr=0.f, ebi=0.f, pwr=1.f, pwi=0.f;
  long base = ((long)b*LL + (long)ch*CHS)*HH;
  for (int i=0;i<CHS;i++){
    float br = bf2f(bub[base + (long)i*HH + p]);
    float bi = bf2f(bub[base + (long)i*HH + 64 + p]);
    float nr = Lr*efr - Li*efi + br;
    efi = Lr*efi + Li*efr + bi; efr = nr;
    ebr += pwr*br - pwi*bi;
    ebi += pwr*bi + pwi*br;
    float tr = pwr*Lr - pwi*Li;
    pwi = pwr*Li + pwi*Lr; pwr = tr;
  }
  long o = ((long)b*NCH + ch)*PP + p;
  ws[OFF_EF + o]       = efr;  ws[OFF_EF+EFS + o]   = efi;
  ws[OFF_EF+2*EFS + o] = ebr;  ws[OFF_EF+3*EFS + o] = ebi;
}

// ================= scan B: carry scan over chunks =================
__global__ void k_scanB(const float* __restrict__ cons, float* __restrict__ ws)
{
  int p = threadIdx.x; int b = blockIdx.x;
  float Cr = cons[128+p], Ci = cons[192+p];
  float Fr=0.f, Fi=0.f;
  for (int ch=0;ch<NCH;ch++){
    long o = ((long)b*NCH + ch)*PP + p;
    ws[OFF_EF+4*EFS + o] = Fr;
    ws[OFF_EF+5*EFS + o] = Fi;
    float er = ws[OFF_EF + o], ei = ws[OFF_EF+EFS + o];
    float nr = Cr*Fr - Ci*Fi + er;
    Fi = Cr*Fi + Ci*Fr + ei; Fr = nr;
  }
  float Xr=0.f, Xi=0.f;
  for (int ch=NCH-1;ch>=0;ch--){
    long o = ((long)b*NCH + ch)*PP + p;
    ws[OFF_EF+6*EFS + o] = Xr;
    ws[OFF_EF+7*EFS + o] = Xi;
    float er = ws[OFF_EF+2*EFS + o], ei = ws[OFF_EF+3*EFS + o];
    float nr = er + Cr*Xr - Ci*Xi;
    Xi = ei + Cr*Xi + Ci*Xr; Xr = nr;
  }
}

// ================= scan C: final inclusive scans; bf16 xf/xb out =================
__global__ void k_scanC(const u16* __restrict__ bub, u16* __restrict__ xfb,
                        u16* __restrict__ xbb, const float* __restrict__ cons,
                        const float* __restrict__ wsc)
{
  int p = threadIdx.x; int ch = blockIdx.x, b = blockIdx.y;
  float Lr = cons[p], Li = cons[64+p];
  long o = ((long)b*NCH + ch)*PP + p;
  float xr = wsc[OFF_EF+4*EFS + o], xi = wsc[OFF_EF+5*EFS + o];
  long base = ((long)b*LL + (long)ch*CHS)*HH;
  for (int i=0;i<CHS;i++){
    long a0 = base + (long)i*HH;
    float br = bf2f(bub[a0+p]), bi = bf2f(bub[a0+64+p]);
    float nr = Lr*xr - Li*xi + br;
    xi = Lr*xi + Li*xr + bi; xr = nr;
    xfb[a0+p] = f2bf(xr); xfb[a0+64+p] = f2bf(xi);
  }
  float yr = wsc[OFF_EF+6*EFS + o], yi = wsc[OFF_EF+7*EFS + o];
  for (int i=CHS-1;i>=0;i--){
    long a0 = base + (long)i*HH;
    float br = bf2f(bub[a0+p]), bi = bf2f(bub[a0+64+p]);
    float nr = Lr*yr - Li*yi + br;
    yi = Lr*yi + Li*yr + bi; yr = nr;
    xbb[a0+p] = f2bf(yr); xbb[a0+64+p] = f2bf(yi);
  }
}

// ================= fused post (register-pressure-shaped):
//  y=xs@Wy; a=gelu(y+D*fx)+fx; fy=LN2(a) (regs + sA);
//  per-ct enc: [v|gt]=fy@Wenc, t=v*gelu(gt)->sA; dec: blk=t@Wdec;
//  h=LN3(blk+fy+h).  After staging, each wave touches ONLY its own
//  32 rows of sA -> no barriers in the enc/dec tail. =================
__global__ __launch_bounds__(256,2) void k_post(const u16* __restrict__ xfb,
                      const u16* __restrict__ xbb, const u16* __restrict__ fxb,
                      const u16* __restrict__ packy, const u16* __restrict__ packe,
                      const u16* __restrict__ packd, float* __restrict__ h,
                      const float* __restrict__ Dv,
                      const float* __restrict__ fg, const float* __restrict__ fb,
                      const float* __restrict__ og, const float* __restrict__ ob)
{
  GEMM_PRE
  ACC_ZERO(fy0, fy1)
  // ---- stage xf, prefetch xb to regs (hide HBM under part-1 MFMAs) ----
  STAGE_BF(xfb);
  bf16x8 pre[8];
  #pragma unroll
  for (int rep=0; rep<8; rep++){ int e = tid + rep*256; int r = e>>4, c8 = (e&15)*8;
    pre[rep] = *(const bf16x8*)(xbb + (g0 + r)*HH + c8); }
  MAINLOOP8(packy, fy0, fy1, 8, 0);
  __syncthreads();
  #pragma unroll
  for (int rep=0; rep<8; rep++){ int e = tid + rep*256; int r = e>>4, c8 = (e&15)*8;
    *(bf16x8*)&sA[r*136 + c8] = pre[rep]; }
  __syncthreads();
  MAINLOOP8(packy, fy0, fy1, 8, 4);
  // ---- a = gelu(y + D*fx) + fx ----
  #define YEPI(ACCA, RT) \
    _Pragma("unroll") for (int ct=0; ct<8; ct++){ int col = ct*16 + c; \
      float dvc = Dv[col]; \
      _Pragma("unroll") for (int q=0;q<4;q++){ \
        int rowL = R0 + (RT)*16 + g*4 + q; \
        float fxv = bf2f(fxb[(g0+rowL)*HH + col]); \
        ACCA[ct][q] = gelu_(ACCA[ct][q] + dvc*fxv) + fxv; } }
  YEPI(fy0, 0)
  YEPI(fy1, 1)
  // ---- LN2 -> fy (kept in regs), bf16 copy into sA own rows ----
  #define YLN(ACCA, RT) \
    _Pragma("unroll") for (int q=0;q<4;q++){ \
      float sm=0.f, sq=0.f; \
      _Pragma("unroll") for (int ct=0;ct<8;ct++){ float v=ACCA[ct][q]; sm+=v; sq+=v*v; } \
      sm += __shfl_xor(sm,1); sq += __shfl_xor(sq,1); \
      sm += __shfl_xor(sm,2); sq += __shfl_xor(sq,2); \
      sm += __shfl_xor(sm,4); sq += __shfl_xor(sq,4); \
      sm += __shfl_xor(sm,8); sq += __shfl_xor(sq,8); \
      float m = sm*(1.0f/HH); \
      float inv = 1.0f/sqrtf(sq*(1.0f/HH) - m*m + 1e-5f); \
      int rowL = R0 + (RT)*16 + g*4 + q; \
      _Pragma("unroll") for (int ct=0;ct<8;ct++){ int col = ct*16 + c; \
        float v = (ACCA[ct][q]-m)*inv*fg[col] + fb[col]; \
        ACCA[ct][q] = v; \
        sA[rowL*136 + col] = f2bf(v); } }
  YLN(fy0, 0)
  YLN(fy1, 1)
  // ---- enc per-ct (peak regs: fy 64 + af 32 + 16 acc) ----
  bf16x8 af0[4], af1[4];
  #pragma unroll
  for (int ks=0; ks<4; ks++){
    af0[ks] = *(const bf16x8*)&sA[(R0 + c)*136 + ks*32 + g*8];
    af1[ks] = *(const bf16x8*)&sA[(R0 + 16 + c)*136 + ks*32 + g*8];
  }
  #pragma unroll
  for (int ct=0; ct<8; ct++){
    f32x4 z = {0.f,0.f,0.f,0.f};
    f32x4 av0=z, av1=z, ag0=z, ag1=z;
    #pragma unroll
    for (int ks=0; ks<4; ks++){
      bf16x8 bv = ((const bf16x8*)packe)[(ct*4 + ks)*64 + lane];
      bf16x8 bg = ((const bf16x8*)packe)[((ct+8)*4 + ks)*64 + lane];
      av0 = __builtin_amdgcn_mfma_f32_16x16x32_bf16(af0[ks], bv, av0, 0,0,0);
      av1 = __builtin_amdgcn_mfma_f32_16x16x32_bf16(af1[ks], bv, av1, 0,0,0);
      ag0 = __builtin_amdgcn_mfma_f32_16x16x32_bf16(af0[ks], bg, ag0, 0,0,0);
      ag1 = __builtin_amdgcn_mfma_f32_16x16x32_bf16(af1[ks], bg, ag1, 0,0,0);
    }
    #pragma unroll
    for (int q=0;q<4;q++){
      sA[(R0 + g*4 + q)*136 + ct*16 + c]      = f2bf(av0[q]*gelu_(ag0[q]));
      sA[(R0 + 16 + g*4 + q)*136 + ct*16 + c] = f2bf(av1[q]*gelu_(ag1[q]));
    }
  }
  // ---- dec GEMM: blk = t @ Wdec (t in sA own rows) ----
  ACC_ZERO(ad0, ad1)
  MAINLOOP8(packd, ad0, ad1, 4, 0);
  // ---- blk + fy + h residual, LN3, write h ----
  #define DADD(AD, AF, RT) \
    _Pragma("unroll") for (int ct=0; ct<8; ct++){ int col = ct*16 + c; \
      _Pragma("unroll") for (int q=0;q<4;q++){ \
        int rowL = R0 + (RT)*16 + g*4 + q; long ix = (g0+rowL)*HH + col; \
        AD[ct][q] += AF[ct][q] + h[ix]; } }
  DADD(ad0, fy0, 0)
  DADD(ad1, fy1, 1)
  #define DLN(ACCA, RT) \
    _Pragma("unroll") for (int q=0;q<4;q++){ \
      float sm=0.f, sq=0.f; \
      _Pragma("unroll") for (int ct=0;ct<8;ct++){ float v=ACCA[ct][q]; sm+=v; sq+=v*v; } \
      sm += __shfl_xor(sm,1); sq += __shfl_xor(sq,1); \
      sm += __shfl_xor(sm,2); sq += __shfl_xor(sq,2); \
      sm += __shfl_xor(sm,4); sq += __shfl_xor(sq,4); \
      sm += __shfl_xor(sm,8); sq += __shfl_xor(sq,8); \
      float m = sm*(1.0f/HH); \
      float inv = 1.0f/sqrtf(sq*(1.0f/HH) - m*m + 1e-5f); \
      int rowL = R0 + (RT)*16 + g*4 + q; \
      _Pragma("unroll") for (int ct=0;ct<8;ct++){ int col = ct*16 + c; \
        h[(g0+rowL)*HH + col] = (ACCA[ct][q]-m)*inv*og[col] + ob[col]; } }
  DLN(ad0, 0)
  DLN(ad1, 1)
}

// ================= mean pool partials =================
__global__ void k_pool(const float* __restrict__ hbuf, float* __restrict__ part)
{
  int hh = threadIdx.x; int seg = blockIdx.x, b = blockIdx.y;
  float sum=0.f;
  long base = ((long)b*LL + (long)seg*128)*HH + hh;
  for (int i=0;i<128;i++) sum += hbuf[base + (long)i*HH];
  part[((long)seg*BB + b)*HH + hh] = sum;
}

// ================= classifier head (fp32 out) =================
__global__ void k_cls(const float* __restrict__ part, const float* __restrict__ Wc1,
                      const float* __restrict__ bc1, const float* __restrict__ Wc2,
                      const float* __restrict__ bc2, float* __restrict__ out)
{
  __shared__ float pooled[BB*HH];
  __shared__ float zs[BB*64];
  int tid = threadIdx.x;
  for (int k=0;k<8;k++){
    int e = tid + k*256; int b = e>>7, hh = e&127;
    float s = 0.f;
    for (int seg=0; seg<64; seg++) s += part[((long)seg*BB + b)*HH + hh];
    pooled[e] = s * (1.0f/(float)LL);
  }
  __syncthreads();
  for (int k=0;k<4;k++){
    int e = tid + k*256; int b = e>>6, j = e&63;
    float s = bc1[j];
    for (int hh=0; hh<HH; hh++) s += pooled[b*HH+hh]*Wc1[hh*64+j];
    zs[e] = fmaxf(s, 0.0f);
  }
  __syncthreads();
  if (tid < BB*3){
    int b = tid/3, cc = tid%3;
    float s = bc2[cc];
    for (int j=0;j<64;j++) s += zs[b*64+j]*Wc2[j*3+cc];
    out[tid] = s;
  }
}

extern "C" void kernel_launch(void* const* d_in, const int* in_sizes, int n_in,
                              void* d_out, int out_size, void* d_ws, size_t ws_size,
                              hipStream_t stream) {
  const float* x       = (const float*)d_in[0];
  const float* W_in    = (const float*)d_in[1];
  const float* b_in    = (const float*)d_in[2];
  const float* attn_g  = (const float*)d_in[3];
  const float* attn_b  = (const float*)d_in[4];
  const float* Lam_re  = (const float*)d_in[5];
  const float* Lam_im  = (const float*)d_in[6];
  const float* B_re    = (const float*)d_in[7];
  const float* B_im    = (const float*)d_in[8];
  const float* C_re    = (const float*)d_in[9];
  const float* C_im    = (const float*)d_in[10];
  const float* Dv      = (const float*)d_in[11];
  const float* log_step= (const float*)d_in[12];
  const float* ff_g    = (const float*)d_in[13];
  const float* ff_b    = (const float*)d_in[14];
  const float* W_enc   = (const float*)d_in[15];
  const float* W_dec   = (const float*)d_in[16];
  const float* out_g   = (const float*)d_in[17];
  const float* out_b   = (const float*)d_in[18];
  const float* Wc1     = (const float*)d_in[19];
  const float* bc1     = (const float*)d_in[20];
  const float* Wc2     = (const float*)d_in[21];
  const float* bc2     = (const float*)d_in[22];
  float* ws = (float*)d_ws;

  float* hbuf = ws + OFF_H;
  u16* fxb = (u16*)(ws + OFF_FX);
  u16* xfb = (u16*)(ws + OFF_XF);
  u16* xbb = (u16*)(ws + OFF_XB);
  u16* bub = (u16*)(ws + OFF_BU);

  k_pre<<<dim3(NLAY,16), 256, 0, stream>>>(Lam_re, Lam_im, B_re, B_im, C_re, C_im,
                                           W_enc, W_dec, log_step, ws);
  k_inproj<<<dim3(LL/256, BB), 256, 0, stream>>>(x, W_in, b_in, hbuf);

  for (int i=0;i<NLAY;i++){
    const u16* pk = (const u16*)(ws + OFF_PC + (unsigned long)i*PCS);
    const float* cons = ws + OFF_PC + (unsigned long)i*PCS + 49152;
    k_ln1<<<ROWS/4, 256, 0, stream>>>(hbuf, fxb, attn_g+i*HH, attn_b+i*HH);
    k_gemm_bu<<<ROWS/128, 256, 0, stream>>>(fxb, pk, bub);
    k_scanA<<<dim3(NCH,BB), 64, 0, stream>>>(bub, cons, ws);
    k_scanB<<<BB, 64, 0, stream>>>(cons, ws);
    k_scanC<<<dim3(NCH,BB), 64, 0, stream>>>(bub, xfb, xbb, cons, ws);
    k_post<<<ROWS/128, 256, 0, stream>>>(xfb, xbb, fxb, pk + 16384, pk + 49152,
                                         pk + 81920, hbuf, Dv+i*HH,
                                         ff_g+i*HH, ff_b+i*HH, out_g+i*HH, out_b+i*HH);
  }
  k_pool<<<dim3(64,BB), 128, 0, stream>>>(hbuf, ws + OFF_EF);
  k_cls<<<1, 256, 0, stream>>>(ws + OFF_EF, Wc1, bc1, Wc2, bc2, (float*)d_out);
}